// Round 10
// baseline (572.707 us; speedup 1.0000x reference)
//
#include <hip/hip_runtime.h>
#include <math.h>

#define BATCH 256
#define NNODE 256
#define FIN   128
#define HID   48
#define DOUT  97

// packed transposed weight planes (ushort elements, per-plane offsets)
#define WOFF_DW0 0        // dW0^T [48][128]
#define WOFF_DW  6144     // dW[i]^T 4 x [48][64]
#define WOFF_UW  18432    // uW[i]^T 3 x [48][64]
#define WOFF_UWL 27648    // uWl^T  [112][64]
#define WTOT     34816    // per-plane stride

typedef __attribute__((ext_vector_type(8))) short bf16x8_t;
typedef __attribute__((ext_vector_type(4))) float f32x4_t;

__device__ inline unsigned short f2bf(float x) {
  unsigned u = __float_as_uint(x);
  u += 0x7fff + ((u >> 16) & 1);
  return (unsigned short)(u >> 16);
}
__device__ inline float bf2f(unsigned short h) {
  return __uint_as_float(((unsigned)h) << 16);
}

// ---------- fused A0 pass: bf16 convert + rowsum -> dinv (exact: 0/1 entries) ----------
__global__ __launch_bounds__(256) void k_prepA(const float* __restrict__ A,
                                               unsigned short* __restrict__ Abf,
                                               float* __restrict__ dinv, int rows) {
  int wid = (blockIdx.x * 256 + threadIdx.x) >> 6;
  int lane = threadIdx.x & 63;
  if (wid >= rows) return;
  const float4* rp = (const float4*)(A + (size_t)wid * 256);
  float4 v = rp[lane];
  unsigned long long pk = (unsigned long long)f2bf(v.x)
                        | ((unsigned long long)f2bf(v.y) << 16)
                        | ((unsigned long long)f2bf(v.z) << 32)
                        | ((unsigned long long)f2bf(v.w) << 48);
  *(unsigned long long*)(Abf + (size_t)wid * 256 + lane * 4) = pk;
  float s = v.x + v.y + v.z + v.w;
  #pragma unroll
  for (int o = 32; o > 0; o >>= 1) s += __shfl_down(s, o);
  if (lane == 0) dinv[wid] = 1.0f / sqrtf(s + 2.0f);
}

// ---------- dinv from bf16 integer adjacency (exact) ----------
__global__ __launch_bounds__(256) void k_dinv_bf(const unsigned short* __restrict__ Abf,
                                                 float* __restrict__ dinv, int n, int rows) {
  int wid = (blockIdx.x * 256 + threadIdx.x) >> 6;
  int lane = threadIdx.x & 63;
  if (wid >= rows) return;
  const unsigned short* row = Abf + (size_t)wid * n;
  float s = 0.f;
  for (int j = lane * 2; j < n; j += 128) {
    unsigned u = *(const unsigned*)(row + j);
    s += bf2f((unsigned short)(u & 0xffffu)) + bf2f((unsigned short)(u >> 16));
  }
  #pragma unroll
  for (int o = 32; o > 0; o >>= 1) s += __shfl_down(s, o);
  if (lane == 0) dinv[wid] = 1.0f / sqrtf(s + 2.0f);
}

// ---------- rowsum -> dinv (fp32 A, deeper levels) ----------
__global__ __launch_bounds__(256) void k_dinv(const float* __restrict__ A,
                                              float* __restrict__ dinv,
                                              int n, int rows) {
  int wid  = (blockIdx.x * blockDim.x + threadIdx.x) >> 6;
  int lane = threadIdx.x & 63;
  if (wid >= rows) return;
  const float* row = A + (size_t)wid * n;
  float s = 0.f;
  for (int j = lane; j < n; j += 64) s += row[j];
  #pragma unroll
  for (int o = 32; o > 0; o >>= 1) s += __shfl_down(s, o);
  if (lane == 0) dinv[wid] = 1.0f / sqrtf(s + 2.0f);
}

// ---------- transpose + 3-plane split ALL weights (runs once, tiny) ----------
__global__ __launch_bounds__(256) void k_splitW3(const float* __restrict__ dW0,
                                                 const float* __restrict__ dW,
                                                 const float* __restrict__ uW,
                                                 const float* __restrict__ uWl,
                                                 unsigned short* __restrict__ Wp) {
  int idx = blockIdx.x * 256 + threadIdx.x;
  if (idx >= WTOT) return;
  float v;
  if (idx < WOFF_DW) {                   // dW0^T [48][128]
    int f = idx / 128, kk = idx - f * 128;
    v = dW0[kk * HID + f];
  } else if (idx < WOFF_UW) {            // dW[i]^T [48][64]
    int r = idx - WOFF_DW;
    int i = r / 3072; r -= i * 3072;
    int f = r / 64, kk = r - f * 64;
    v = (kk < HID) ? dW[((size_t)i * HID + kk) * HID + f] : 0.f;
  } else if (idx < WOFF_UWL) {           // uW[i]^T [48][64]
    int r = idx - WOFF_UW;
    int i = r / 3072; r -= i * 3072;
    int f = r / 64, kk = r - f * 64;
    v = (kk < HID) ? uW[((size_t)i * HID + kk) * HID + f] : 0.f;
  } else {                               // uWl^T [112][64]
    int r = idx - WOFF_UWL;
    int f = r / 64, kk = r - f * 64;
    v = (f < DOUT && kk < HID) ? uWl[(size_t)kk * DOUT + f] : 0.f;
  }
  unsigned short h = f2bf(v);
  float r1 = v - bf2f(h);
  unsigned short m = f2bf(r1);
  float r2 = r1 - bf2f(m);
  unsigned short l = f2bf(r2);
  Wp[idx] = h;
  Wp[idx + WTOT] = m;
  Wp[idx + 2 * WTOT] = l;
}

// ---------- wave-independent MFMA GEMM XW = X @ W, 3-plane split, NO LDS/barrier ----------
// Optional epilogues: fp32 XW store (if XW != null) and/or transposed split-Y planes
// Yt[b][f][j] = split(dinv[row]*acc) (if Yth != null; lane layout is already transposed).
template<int KS2>   // K-steps of 32; KP = KS2*32
__global__ __launch_bounds__(256) void k_xws(const float* __restrict__ X,
                                             const unsigned short* __restrict__ Wp,
                                             float* __restrict__ XW,
                                             const float* __restrict__ dinv,
                                             unsigned short* __restrict__ Yth,
                                             unsigned short* __restrict__ Ytl,
                                             int K, int F, int Fpad, int nShift) {
  constexpr int KP = KS2 * 32;
  int mt = (blockIdx.x * 256 + threadIdx.x) >> 6;
  int lane = threadIdx.x & 63;
  int r = lane & 15, q = lane >> 4;
  const float* xr = X + ((long)mt * 16 + r) * K;
  bf16x8_t ah[KS2], am[KS2], al[KS2];
  #pragma unroll
  for (int ks = 0; ks < KS2; ks++) {
    int col0 = ks * 32 + q * 8;
    float v[8];
    if (col0 + 8 <= K) {
      float4 a = *(const float4*)(xr + col0);
      float4 b = *(const float4*)(xr + col0 + 4);
      v[0] = a.x; v[1] = a.y; v[2] = a.z; v[3] = a.w;
      v[4] = b.x; v[5] = b.y; v[6] = b.z; v[7] = b.w;
    } else {
      #pragma unroll
      for (int j = 0; j < 8; j++) v[j] = (col0 + j < K) ? xr[col0 + j] : 0.f;
    }
    #pragma unroll
    for (int j = 0; j < 8; j++) {
      unsigned short h = f2bf(v[j]);
      float r1 = v[j] - bf2f(h);
      unsigned short m = f2bf(r1);
      float r2 = r1 - bf2f(m);
      unsigned short l = f2bf(r2);
      ah[ks][j] = (short)h;
      am[ks][j] = (short)m;
      al[ks][j] = (short)l;
    }
  }
  long row0 = (long)mt * 16 + q * 4;        // 4 consecutive output rows per lane
  float4 dv4 = {0.f, 0.f, 0.f, 0.f};
  long ytBase = 0;
  if (Yth) {
    dv4 = *(const float4*)(dinv + row0);
    int bb = (int)(row0 >> nShift);
    int jj = (int)(row0 & ((1 << nShift) - 1));
    ytBase = (long)bb * Fpad;
    ytBase = ytBase << nShift;
    ytBase += jj;
  }
  int nFT = Fpad >> 4;
  for (int ft = 0; ft < nFT; ft++) {
    int fl = ft * 16 + r;
    const unsigned short* wb = Wp + (size_t)fl * KP + q * 8;
    f32x4_t acc = {0.f, 0.f, 0.f, 0.f};
    #pragma unroll
    for (int ks = 0; ks < KS2; ks++) {
      bf16x8_t bh = *(const bf16x8_t*)(wb + ks * 32);
      bf16x8_t bm = *(const bf16x8_t*)(wb + WTOT + ks * 32);
      bf16x8_t bl = *(const bf16x8_t*)(wb + 2 * WTOT + ks * 32);
      acc = __builtin_amdgcn_mfma_f32_16x16x32_bf16(ah[ks], bh, acc, 0, 0, 0);
      acc = __builtin_amdgcn_mfma_f32_16x16x32_bf16(ah[ks], bm, acc, 0, 0, 0);
      acc = __builtin_amdgcn_mfma_f32_16x16x32_bf16(am[ks], bh, acc, 0, 0, 0);
      acc = __builtin_amdgcn_mfma_f32_16x16x32_bf16(am[ks], bm, acc, 0, 0, 0);
      acc = __builtin_amdgcn_mfma_f32_16x16x32_bf16(ah[ks], bl, acc, 0, 0, 0);
      acc = __builtin_amdgcn_mfma_f32_16x16x32_bf16(al[ks], bh, acc, 0, 0, 0);
    }
    int f = fl;
    if (f < F) {
      if (XW) {
        #pragma unroll
        for (int reg = 0; reg < 4; reg++) XW[(row0 + reg) * F + f] = acc[reg];
      }
      if (Yth) {
        float dvv[4] = {dv4.x, dv4.y, dv4.z, dv4.w};
        unsigned long long hpk = 0, lpk = 0;
        #pragma unroll
        for (int reg = 0; reg < 4; reg++) {
          float v = dvv[reg] * acc[reg];
          unsigned short hi = f2bf(v);
          unsigned short lo = f2bf(v - bf2f(hi));
          hpk |= ((unsigned long long)hi) << (16 * reg);
          lpk |= ((unsigned long long)lo) << (16 * reg);
        }
        long o = ytBase + ((long)f << nShift);
        *(unsigned long long*)(Yth + o) = hpk;
        *(unsigned long long*)(Ytl + o) = lpk;
      }
    }
  }
}

// ---------- LDS-free fused GCN: one it-tile per wave, A frags in regs, Yt from L2 ----------
// out[b,i,f] = relu?( d_i*(A@(Yh+Yl)) + 2 d_i*Y[f][i] + bias_f ), Y[f][i]=Yh+Yl ≈ d_i*xw_if
// grid = (n/64) * BATCH; b = blockIdx&255 (same-batch blocks share an XCD)
template<int KS>
__global__ __launch_bounds__(256) void k_gcn2(
    const unsigned short* __restrict__ Abf, const float* __restrict__ dinv,
    const unsigned short* __restrict__ Yth, const unsigned short* __restrict__ Ytl,
    const float* __restrict__ bias, float* __restrict__ out,
    int F, int Fpad, int dorelu) {
  constexpr int n = KS * 32;
  int b = blockIdx.x & (BATCH - 1);
  int sub = blockIdx.x >> 8;
  int wave = threadIdx.x >> 6, lane = threadIdx.x & 63;
  int r = lane & 15, q = lane >> 4;
  const float* dv = dinv + (size_t)b * n;
  int it = sub * 4 + wave;
  const unsigned short* ap = Abf + ((size_t)b * n + it * 16 + r) * n + q * 8;
  bf16x8_t af[KS];
  #pragma unroll
  for (int ks = 0; ks < KS; ks++) af[ks] = *(const bf16x8_t*)(ap + ks * 32);
  int i0 = it * 16 + q * 4;
  float di[4];
  #pragma unroll
  for (int reg = 0; reg < 4; reg++) di[reg] = dv[i0 + reg];
  int nFT = Fpad >> 4;
  for (int ft = 0; ft < nFT; ft++) {
    int fl = ft * 16 + r;
    const unsigned short* yh = Yth + ((size_t)b * Fpad + fl) * n;
    const unsigned short* yl = Ytl + ((size_t)b * Fpad + fl) * n;
    f32x4_t acc = {0.f, 0.f, 0.f, 0.f};
    #pragma unroll
    for (int ks = 0; ks < KS; ks++) {
      bf16x8_t bh = *(const bf16x8_t*)(yh + q * 8 + ks * 32);
      bf16x8_t bl = *(const bf16x8_t*)(yl + q * 8 + ks * 32);
      acc = __builtin_amdgcn_mfma_f32_16x16x32_bf16(af[ks], bh, acc, 0, 0, 0);
      acc = __builtin_amdgcn_mfma_f32_16x16x32_bf16(af[ks], bl, acc, 0, 0, 0);
    }
    if (fl < F) {
      unsigned long long hq = *(const unsigned long long*)(yh + i0);
      unsigned long long lq = *(const unsigned long long*)(yl + i0);
      float bf = bias[fl];
      #pragma unroll
      for (int reg = 0; reg < 4; reg++) {
        float yv = bf2f((unsigned short)(hq >> (16 * reg)))
                 + bf2f((unsigned short)(lq >> (16 * reg)));
        float v = di[reg] * acc[reg] + 2.f * di[reg] * yv + bf;
        if (dorelu) v = fmaxf(v, 0.f);
        out[((size_t)b * n + i0 + reg) * F + fl] = v;
      }
    }
  }
}

// ---------- MFMA augment (EXACT integer arithmetic) ----------
__global__ __launch_bounds__(256) void k_aug_mfma(const unsigned short* __restrict__ Abf,
                                                  const int* __restrict__ perm,
                                                  float* __restrict__ Ap,
                                                  unsigned short* __restrict__ Apbf,
                                                  int n, int k, int nTiles) {
  int wid = (blockIdx.x * 256 + threadIdx.x) >> 6;
  if (wid >= nTiles) return;
  int lane = threadIdx.x & 63;
  int kt = k >> 4;
  int b = wid / (kt * kt);
  int rem = wid - b * (kt * kt);
  int it = rem / kt, ft = rem - it * kt;
  int r = lane & 15, q = lane >> 4;
  const int* pm = perm + (size_t)b * k;
  int rowA = pm[it * 16 + r];
  int rowB = pm[ft * 16 + r];
  const unsigned short* Ab = Abf + (size_t)b * n * n;
  const unsigned short* pa = Ab + (size_t)rowA * n + q * 8;
  const unsigned short* pb = Ab + (size_t)rowB * n + q * 8;
  f32x4_t acc = {0.f, 0.f, 0.f, 0.f};
  for (int k0 = 0; k0 < n; k0 += 32) {
    bf16x8_t a  = *(const bf16x8_t*)(pa + k0);
    bf16x8_t bv = *(const bf16x8_t*)(pb + k0);
    acc = __builtin_amdgcn_mfma_f32_16x16x32_bf16(a, bv, acc, 0, 0, 0);
  }
  int c = ft * 16 + r;
  const unsigned short* rowBp = Ab + (size_t)rowB * n;
  #pragma unroll
  for (int reg = 0; reg < 4; reg++) {
    int rr = it * 16 + q * 4 + reg;
    int pr = pm[rr];
    float v = acc[reg] + 2.f * bf2f(rowBp[pr]);
    if (rr == c) v = 0.f;
    if (Ap)   Ap[((size_t)b * k + rr) * k + c] = v;
    if (Apbf) Apbf[((size_t)b * k + rr) * k + c] = f2bf(v);
  }
}

// ---------- VALU augment for tiny levels ----------
__global__ __launch_bounds__(256) void k_aug(const float* __restrict__ A,
                                             const int* __restrict__ perm,
                                             float* __restrict__ Ap,
                                             int n, int k) {
  int b = blockIdx.y, r0 = blockIdx.x * 4, t = threadIdx.x;
  __shared__ float sR[4 * 256];
  __shared__ int spm[4];
  const float* Ab = A + (size_t)b * n * n;
  if (t < 4) spm[t] = perm[(size_t)b * k + r0 + t];
  __syncthreads();
  for (int idx = t; idx < 4 * n; idx += 256) {
    int rl = idx / n, j = idx - rl * n;
    sR[rl * n + j] = Ab[(size_t)spm[rl] * n + j];
  }
  __syncthreads();
  for (int c = t; c < k; c += 256) {
    int pc = perm[(size_t)b * k + c];
    const float* rowc = Ab + (size_t)pc * n;
    float a0 = 0.f, a1 = 0.f, a2 = 0.f, a3 = 0.f;
    for (int j = 0; j < n; j++) {
      float v = rowc[j];
      a0 += sR[j] * v;
      a1 += sR[n + j] * v;
      a2 += sR[2 * n + j] * v;
      a3 += sR[3 * n + j] * v;
    }
    float accs[4] = {a0, a1, a2, a3};
    for (int rl = 0; rl < 4; rl++) {
      int r = r0 + rl;
      float res = accs[rl] + 2.f * Ab[(size_t)spm[rl] * n + pc];
      Ap[((size_t)b * k + r) * k + c] = (r == c) ? 0.f : res;
    }
  }
}

// ---------- VALU anxw for small n ----------
__global__ __launch_bounds__(256) void k_anxw(const float* __restrict__ A,
                                              const float* __restrict__ dinv,
                                              const float* __restrict__ xw,
                                              const float* __restrict__ bias,
                                              float* __restrict__ out,
                                              int n, int F, int dorelu) {
  int b = blockIdx.y, i0 = blockIdx.x * 4, t = threadIdx.x;
  __shared__ float sA[4 * 256];
  const float* Ab = A + (size_t)b * n * n;
  const float* dv = dinv + (size_t)b * n;
  for (int idx = t; idx < 4 * n; idx += 256) {
    int il = idx / n, j = idx - il * n;
    sA[il * n + j] = Ab[(size_t)(i0 + il) * n + j] * dv[j];
  }
  __syncthreads();
  const float* xwb = xw + (size_t)b * n * F;
  for (int idx = t; idx < 4 * F; idx += 256) {
    int il = idx / F, f = idx - il * F;
    int i = i0 + il;
    const float* sr = &sA[il * n];
    float acc = 0.f;
    for (int j = 0; j < n; j++) acc += sr[j] * xwb[(size_t)j * F + f];
    float di = dv[i];
    float v = di * acc + 2.f * di * di * xwb[(size_t)i * F + f] + bias[f];
    if (dorelu) v = fmaxf(v, 0.f);
    out[((size_t)b * n + i) * F + f] = v;
  }
}

// ---------- fused pooling: score + exact top-k rank + gather ----------
__global__ __launch_bounds__(256) void k_pool(const float* __restrict__ H,
                                              const float* __restrict__ p,
                                              int* __restrict__ perm,
                                              float* __restrict__ Hout,
                                              int n, int k) {
  int b = blockIdx.x, t = threadIdx.x;
  __shared__ float s[256];
  __shared__ int sord[128];
  float pn = 0.f;
  #pragma unroll
  for (int j = 0; j < HID; j++) pn += p[j] * p[j];
  if (t < n) {
    const float* hr = H + ((size_t)b * n + t) * HID;
    float acc = 0.f;
    #pragma unroll
    for (int j = 0; j < HID; j++) acc += hr[j] * p[j];
    s[t] = tanhf(acc / sqrtf(pn));
  }
  __syncthreads();
  if (t < n) {
    float v = s[t];
    int r = 0;
    for (int j = 0; j < n; j++) {
      float u = s[j];
      r += (u > v) || (u == v && j < t);
    }
    if (r < k) { perm[(size_t)b * k + r] = t; sord[r] = t; }
  }
  __syncthreads();
  for (int idx = t; idx < k * HID; idx += 256) {
    int r = idx / HID, f = idx - r * HID;
    int pi = sord[r];
    Hout[((size_t)b * k + r) * HID + f] = H[((size_t)b * n + pi) * HID + f] * s[pi];
  }
}

// ---------- decoder scatter-add ----------
__global__ __launch_bounds__(256) void k_scatter(const int* __restrict__ perm,
                                                 const float* __restrict__ Hsrc,
                                                 float* __restrict__ Hdst,
                                                 int n, int k, int total) {
  int idx = blockIdx.x * 256 + threadIdx.x;
  if (idx >= total) return;
  int f = idx % HID;
  int r = (idx / HID) % k;
  int b = idx / (HID * k);
  int pi = perm[(size_t)b * k + r];
  Hdst[((size_t)b * n + pi) * HID + f] += Hsrc[idx];
}

// ---------- fused head ----------
__global__ __launch_bounds__(256) void k_head(const float* __restrict__ HT,
                                              const float* __restrict__ c1W,
                                              const float* __restrict__ c1b,
                                              const float* __restrict__ c2W,
                                              const float* __restrict__ c2b,
                                              const float* __restrict__ oW,
                                              const float* __restrict__ ob,
                                              float* __restrict__ out) {
  int b = blockIdx.x, t = threadIdx.x;
  __shared__ float sc[256];
  __shared__ int ord[30];
  __shared__ float sp[30 * 97];
  __shared__ float y1[16 * 30];
  __shared__ float yp[16 * 15];
  __shared__ float yc[32 * 11];
  const float* Hb = HT + (size_t)b * NNODE * DOUT;
  sc[t] = Hb[(size_t)t * DOUT + (DOUT - 1)];
  __syncthreads();
  {
    float v = sc[t];
    int r = 0;
    for (int j = 0; j < 256; j++) {
      float u = sc[j];
      r += (u > v) || (u == v && j < t);
    }
    if (r < 30) ord[r] = t;
  }
  __syncthreads();
  for (int idx = t; idx < 30 * 97; idx += 256) {
    int r = idx / 97, d = idx - r * 97;
    sp[idx] = Hb[(size_t)ord[r] * DOUT + d];
  }
  __syncthreads();
  for (int idx = t; idx < 16 * 30; idx += 256) {
    int c = idx / 30, kk = idx - c * 30;
    float a = c1b[c];
    for (int d = 0; d < 97; d++) a += sp[kk * 97 + d] * c1W[c * 97 + d];
    y1[c * 30 + kk] = fmaxf(a, 0.f);
  }
  __syncthreads();
  for (int idx = t; idx < 16 * 15; idx += 256) {
    int c = idx / 15, t2 = idx - c * 15;
    yp[idx] = fmaxf(y1[c * 30 + 2 * t2], y1[c * 30 + 2 * t2 + 1]);
  }
  __syncthreads();
  for (int idx = t; idx < 32 * 11; idx += 256) {
    int o = idx / 11, t3 = idx - o * 11;
    float a = c2b[o];
    for (int i2 = 0; i2 < 16; i2++)
      for (int w = 0; w < 5; w++)
        a += yp[i2 * 15 + t3 + w] * c2W[(o * 16 + i2) * 5 + w];
    yc[o * 11 + t3] = fmaxf(a, 0.f);
  }
  __syncthreads();
  if (t < 32) {
    float a = ob[t];
    for (int q = 0; q < 352; q++) a += yc[q] * oW[q * 32 + t];
    out[(size_t)b * 32 + t] = fmaxf(a, 0.f);
  }
}

extern "C" void kernel_launch(void* const* d_in, const int* in_sizes, int n_in,
                              void* d_out, int out_size, void* d_ws, size_t ws_size,
                              hipStream_t stream) {
  const float* x   = (const float*)d_in[0];
  const float* A0  = (const float*)d_in[1];
  const float* dW0 = (const float*)d_in[2];
  const float* db0 = (const float*)d_in[3];
  const float* dW  = (const float*)d_in[4];
  const float* dbv = (const float*)d_in[5];
  const float* pp  = (const float*)d_in[6];
  const float* uW  = (const float*)d_in[7];
  const float* ub  = (const float*)d_in[8];
  const float* uWl = (const float*)d_in[9];
  const float* ubl = (const float*)d_in[10];
  const float* c1W = (const float*)d_in[11];
  const float* c1b = (const float*)d_in[12];
  const float* c2W = (const float*)d_in[13];
  const float* c2b = (const float*)d_in[14];
  const float* oW  = (const float*)d_in[15];
  const float* ob  = (const float*)d_in[16];
  float* out = (float*)d_out;

  float* base = (float*)d_ws;
  size_t off = 0;
  auto alloc = [&](size_t nel) { nel = (nel + 3) & ~(size_t)3; float* p = base + off; off += nel; return p; };
  float* H0 = alloc((size_t)BATCH * 256 * HID);
  float* H1 = alloc((size_t)BATCH * 128 * HID);
  float* H2 = alloc((size_t)BATCH * 64 * HID);
  float* H3 = alloc((size_t)BATCH * 32 * HID);
  float* H4 = alloc((size_t)BATCH * 16 * HID);
  float* HT = alloc((size_t)BATCH * 256 * DOUT);
  float* XW = alloc((size_t)BATCH * 256 * DOUT);
  float* A2 = alloc((size_t)BATCH * 64 * 64);
  float* A3 = alloc((size_t)BATCH * 32 * 32);
  float* A4 = alloc((size_t)BATCH * 16 * 16);
  float* D0 = alloc((size_t)BATCH * 256);
  float* D1 = alloc((size_t)BATCH * 128);
  float* D2 = alloc((size_t)BATCH * 64);
  float* D3 = alloc((size_t)BATCH * 32);
  float* D4 = alloc((size_t)BATCH * 16);
  int* P1 = (int*)alloc((size_t)BATCH * 128);
  int* P2 = (int*)alloc((size_t)BATCH * 64);
  int* P3 = (int*)alloc((size_t)BATCH * 32);
  int* P4 = (int*)alloc((size_t)BATCH * 16);
  unsigned short* Abf0 = (unsigned short*)alloc((size_t)BATCH * 256 * 256 / 2);
  unsigned short* Abf1 = (unsigned short*)alloc((size_t)BATCH * 128 * 128 / 2);
  unsigned short* Yth  = (unsigned short*)alloc((size_t)BATCH * 112 * 256 / 2);
  unsigned short* Ytl  = (unsigned short*)alloc((size_t)BATCH * 112 * 256 / 2);
  unsigned short* Wp   = (unsigned short*)alloc((size_t)3 * WTOT / 2 + 4);

  int ns[5] = {256, 128, 64, 32, 16};
  float* Hl[5] = {H0, H1, H2, H3, H4};
  float* Al[5] = {nullptr, nullptr, A2, A3, A4};
  float* Dl[5] = {D0, D1, D2, D3, D4};
  int* Pl[4] = {P1, P2, P3, P4};

  // ---- prologue ----
  k_prepA<<<BATCH * 256 / 4, 256, 0, stream>>>(A0, Abf0, D0, BATCH * 256);
  k_splitW3<<<(WTOT + 255) / 256, 256, 0, stream>>>(dW0, dW, uW, uWl, Wp);

  // ---- first GCN: xws (Yt only), LDS-free gcn2 ----
  {
    k_xws<4><<<BATCH * 256 / 64, 256, 0, stream>>>(x, Wp + WOFF_DW0, nullptr,
                                                   D0, Yth, Ytl, FIN, HID, 48, 8);
    k_gcn2<8><<<BATCH * 4, 256, 0, stream>>>(Abf0, D0, Yth, Ytl, db0, H0, HID, 48, 1);
  }

  // ---- encoder levels ----
  for (int i = 0; i < 4; i++) {
    int n = ns[i], kk = ns[i + 1];
    k_pool<<<BATCH, 256, 0, stream>>>(Hl[i], pp + i * HID, Pl[i], Hl[i + 1], n, kk);
    if (i == 0) {
      int nT = BATCH * 8 * 8;
      k_aug_mfma<<<(nT + 3) / 4, 256, 0, stream>>>(Abf0, P1, nullptr, Abf1, 256, 128, nT);
      k_dinv_bf<<<BATCH * 128 / 4, 256, 0, stream>>>(Abf1, D1, 128, BATCH * 128);
    } else if (i == 1) {
      int nT = BATCH * 4 * 4;
      k_aug_mfma<<<(nT + 3) / 4, 256, 0, stream>>>(Abf1, P2, A2, nullptr, 128, 64, nT);
      k_dinv<<<BATCH * 64 / 4, 256, 0, stream>>>(A2, D2, 64, BATCH * 64);
    } else {
      k_aug<<<dim3(kk / 4, BATCH), 256, 0, stream>>>(Al[i], Pl[i], Al[i + 1], n, kk);
      k_dinv<<<(BATCH * kk + 3) / 4, 256, 0, stream>>>(Al[i + 1], Dl[i + 1], kk, BATCH * kk);
    }
    if (kk == 128) {
      k_xws<2><<<BATCH * kk / 64, 256, 0, stream>>>(Hl[i + 1], Wp + WOFF_DW + i * 3072,
                                                    nullptr, D1, Yth, Ytl, HID, HID, 48, 7);
      k_gcn2<4><<<BATCH * 2, 256, 0, stream>>>(Abf1, D1, Yth, Ytl, dbv + i * HID,
                                               Hl[i + 1], HID, 48, 1);
    } else {
      k_xws<2><<<BATCH * kk / 64, 256, 0, stream>>>(Hl[i + 1], Wp + WOFF_DW + i * 3072,
                                                    XW, nullptr, nullptr, nullptr,
                                                    HID, HID, 48, 0);
      k_anxw<<<dim3(kk / 4, BATCH), 256, 0, stream>>>(Al[i + 1], Dl[i + 1], XW,
                                                      dbv + i * HID, Hl[i + 1], kk, HID, 1);
    }
  }

  // ---- decoder ----
  for (int i = 0; i < 4; i++) {
    int j = 3 - i, nj = ns[j], kj = ns[j + 1];
    k_scatter<<<(BATCH * kj * HID + 255) / 256, 256, 0, stream>>>(Pl[j], Hl[j + 1], Hl[j],
                                                                  nj, kj, BATCH * kj * HID);
    if (i < 3) {
      if (nj == 128) {
        k_xws<2><<<BATCH * nj / 64, 256, 0, stream>>>(Hl[j], Wp + WOFF_UW + i * 3072,
                                                      nullptr, D1, Yth, Ytl, HID, HID, 48, 7);
        k_gcn2<4><<<BATCH * 2, 256, 0, stream>>>(Abf1, D1, Yth, Ytl, ub + i * HID,
                                                 Hl[j], HID, 48, 1);
      } else {
        k_xws<2><<<BATCH * nj / 64, 256, 0, stream>>>(Hl[j], Wp + WOFF_UW + i * 3072,
                                                      XW, nullptr, nullptr, nullptr,
                                                      HID, HID, 48, 0);
        k_anxw<<<dim3(nj / 4, BATCH), 256, 0, stream>>>(Al[j], Dl[j], XW, ub + i * HID,
                                                        Hl[j], nj, HID, 1);
      }
    } else {
      k_xws<2><<<BATCH * 256 / 64, 256, 0, stream>>>(H0, Wp + WOFF_UWL, nullptr,
                                                     D0, Yth, Ytl, HID, DOUT, 112, 8);
      k_gcn2<8><<<BATCH * 4, 256, 0, stream>>>(Abf0, D0, Yth, Ytl, ubl, HT, DOUT, 112, 0);
    }
  }

  // ---- fused head ----
  k_head<<<BATCH, 256, 0, stream>>>(HT, c1W, c1b, c2W, c2b, oW, ob, out);
}

// Round 11
// 545.821 us; speedup vs baseline: 1.0493x; 1.0493x over previous
//
#include <hip/hip_runtime.h>
#include <math.h>

#define BATCH 256
#define NNODE 256
#define FIN   128
#define HID   48
#define DOUT  97

// packed transposed weight planes (ushort elements, per-plane offsets)
#define WOFF_DW0 0        // dW0^T [48][128]
#define WOFF_DW  6144     // dW[i]^T 4 x [48][64]
#define WOFF_UW  18432    // uW[i]^T 3 x [48][64]
#define WOFF_UWL 27648    // uWl^T  [112][64]
#define WTOT     34816    // per-plane stride

typedef __attribute__((ext_vector_type(8))) short bf16x8_t;
typedef __attribute__((ext_vector_type(4))) float f32x4_t;

__device__ inline unsigned short f2bf(float x) {
  unsigned u = __float_as_uint(x);
  u += 0x7fff + ((u >> 16) & 1);
  return (unsigned short)(u >> 16);
}
__device__ inline float bf2f(unsigned short h) {
  return __uint_as_float(((unsigned)h) << 16);
}

// ---------- fused A0 pass: bf16 convert + rowsum -> dinv (exact: 0/1 entries) ----------
__global__ __launch_bounds__(256) void k_prepA(const float* __restrict__ A,
                                               unsigned short* __restrict__ Abf,
                                               float* __restrict__ dinv, int rows) {
  int wid = (blockIdx.x * 256 + threadIdx.x) >> 6;
  int lane = threadIdx.x & 63;
  if (wid >= rows) return;
  const float4* rp = (const float4*)(A + (size_t)wid * 256);
  float4 v = rp[lane];
  unsigned long long pk = (unsigned long long)f2bf(v.x)
                        | ((unsigned long long)f2bf(v.y) << 16)
                        | ((unsigned long long)f2bf(v.z) << 32)
                        | ((unsigned long long)f2bf(v.w) << 48);
  *(unsigned long long*)(Abf + (size_t)wid * 256 + lane * 4) = pk;
  float s = v.x + v.y + v.z + v.w;
  #pragma unroll
  for (int o = 32; o > 0; o >>= 1) s += __shfl_down(s, o);
  if (lane == 0) dinv[wid] = 1.0f / sqrtf(s + 2.0f);
}

// ---------- dinv from bf16 integer adjacency (exact) ----------
__global__ __launch_bounds__(256) void k_dinv_bf(const unsigned short* __restrict__ Abf,
                                                 float* __restrict__ dinv, int n, int rows) {
  int wid = (blockIdx.x * 256 + threadIdx.x) >> 6;
  int lane = threadIdx.x & 63;
  if (wid >= rows) return;
  const unsigned short* row = Abf + (size_t)wid * n;
  float s = 0.f;
  for (int j = lane * 2; j < n; j += 128) {
    unsigned u = *(const unsigned*)(row + j);
    s += bf2f((unsigned short)(u & 0xffffu)) + bf2f((unsigned short)(u >> 16));
  }
  #pragma unroll
  for (int o = 32; o > 0; o >>= 1) s += __shfl_down(s, o);
  if (lane == 0) dinv[wid] = 1.0f / sqrtf(s + 2.0f);
}

// ---------- rowsum -> dinv (fp32 A, deeper levels) ----------
__global__ __launch_bounds__(256) void k_dinv(const float* __restrict__ A,
                                              float* __restrict__ dinv,
                                              int n, int rows) {
  int wid  = (blockIdx.x * blockDim.x + threadIdx.x) >> 6;
  int lane = threadIdx.x & 63;
  if (wid >= rows) return;
  const float* row = A + (size_t)wid * n;
  float s = 0.f;
  for (int j = lane; j < n; j += 64) s += row[j];
  #pragma unroll
  for (int o = 32; o > 0; o >>= 1) s += __shfl_down(s, o);
  if (lane == 0) dinv[wid] = 1.0f / sqrtf(s + 2.0f);
}

// ---------- transpose + 3-plane split ALL weights (runs once, tiny) ----------
__global__ __launch_bounds__(256) void k_splitW3(const float* __restrict__ dW0,
                                                 const float* __restrict__ dW,
                                                 const float* __restrict__ uW,
                                                 const float* __restrict__ uWl,
                                                 unsigned short* __restrict__ Wp) {
  int idx = blockIdx.x * 256 + threadIdx.x;
  if (idx >= WTOT) return;
  float v;
  if (idx < WOFF_DW) {                   // dW0^T [48][128]
    int f = idx / 128, kk = idx - f * 128;
    v = dW0[kk * HID + f];
  } else if (idx < WOFF_UW) {            // dW[i]^T [48][64]
    int r = idx - WOFF_DW;
    int i = r / 3072; r -= i * 3072;
    int f = r / 64, kk = r - f * 64;
    v = (kk < HID) ? dW[((size_t)i * HID + kk) * HID + f] : 0.f;
  } else if (idx < WOFF_UWL) {           // uW[i]^T [48][64]
    int r = idx - WOFF_UW;
    int i = r / 3072; r -= i * 3072;
    int f = r / 64, kk = r - f * 64;
    v = (kk < HID) ? uW[((size_t)i * HID + kk) * HID + f] : 0.f;
  } else {                               // uWl^T [112][64]
    int r = idx - WOFF_UWL;
    int f = r / 64, kk = r - f * 64;
    v = (f < DOUT && kk < HID) ? uWl[(size_t)kk * DOUT + f] : 0.f;
  }
  unsigned short h = f2bf(v);
  float r1 = v - bf2f(h);
  unsigned short m = f2bf(r1);
  float r2 = r1 - bf2f(m);
  unsigned short l = f2bf(r2);
  Wp[idx] = h;
  Wp[idx + WTOT] = m;
  Wp[idx + 2 * WTOT] = l;
}

// ---------- wave-independent MFMA GEMM XW = X @ W, 3-plane split, NO LDS/barrier ----------
// Optional epilogues: fp32 XW store (if XW != null) and/or transposed split-Y planes
// Yt[b][f][j] = split(dinv[row]*acc) (if Yth != null; lane layout is already transposed).
template<int KS2>   // K-steps of 32; KP = KS2*32
__global__ __launch_bounds__(256) void k_xws(const float* __restrict__ X,
                                             const unsigned short* __restrict__ Wp,
                                             float* __restrict__ XW,
                                             const float* __restrict__ dinv,
                                             unsigned short* __restrict__ Yth,
                                             unsigned short* __restrict__ Ytl,
                                             int K, int F, int Fpad, int nShift) {
  constexpr int KP = KS2 * 32;
  int mt = (blockIdx.x * 256 + threadIdx.x) >> 6;
  int lane = threadIdx.x & 63;
  int r = lane & 15, q = lane >> 4;
  const float* xr = X + ((long)mt * 16 + r) * K;
  bf16x8_t ah[KS2], am[KS2], al[KS2];
  #pragma unroll
  for (int ks = 0; ks < KS2; ks++) {
    int col0 = ks * 32 + q * 8;
    float v[8];
    if (col0 + 8 <= K) {
      float4 a = *(const float4*)(xr + col0);
      float4 b = *(const float4*)(xr + col0 + 4);
      v[0] = a.x; v[1] = a.y; v[2] = a.z; v[3] = a.w;
      v[4] = b.x; v[5] = b.y; v[6] = b.z; v[7] = b.w;
    } else {
      #pragma unroll
      for (int j = 0; j < 8; j++) v[j] = (col0 + j < K) ? xr[col0 + j] : 0.f;
    }
    #pragma unroll
    for (int j = 0; j < 8; j++) {
      unsigned short h = f2bf(v[j]);
      float r1 = v[j] - bf2f(h);
      unsigned short m = f2bf(r1);
      float r2 = r1 - bf2f(m);
      unsigned short l = f2bf(r2);
      ah[ks][j] = (short)h;
      am[ks][j] = (short)m;
      al[ks][j] = (short)l;
    }
  }
  long row0 = (long)mt * 16 + q * 4;        // 4 consecutive output rows per lane
  float4 dv4 = {0.f, 0.f, 0.f, 0.f};
  long ytBase = 0;
  if (Yth) {
    dv4 = *(const float4*)(dinv + row0);
    int bb = (int)(row0 >> nShift);
    int jj = (int)(row0 & ((1 << nShift) - 1));
    ytBase = (long)bb * Fpad;
    ytBase = ytBase << nShift;
    ytBase += jj;
  }
  int nFT = Fpad >> 4;
  for (int ft = 0; ft < nFT; ft++) {
    int fl = ft * 16 + r;
    const unsigned short* wb = Wp + (size_t)fl * KP + q * 8;
    f32x4_t acc = {0.f, 0.f, 0.f, 0.f};
    #pragma unroll
    for (int ks = 0; ks < KS2; ks++) {
      bf16x8_t bh = *(const bf16x8_t*)(wb + ks * 32);
      bf16x8_t bm = *(const bf16x8_t*)(wb + WTOT + ks * 32);
      bf16x8_t bl = *(const bf16x8_t*)(wb + 2 * WTOT + ks * 32);
      acc = __builtin_amdgcn_mfma_f32_16x16x32_bf16(ah[ks], bh, acc, 0, 0, 0);
      acc = __builtin_amdgcn_mfma_f32_16x16x32_bf16(ah[ks], bm, acc, 0, 0, 0);
      acc = __builtin_amdgcn_mfma_f32_16x16x32_bf16(am[ks], bh, acc, 0, 0, 0);
      acc = __builtin_amdgcn_mfma_f32_16x16x32_bf16(am[ks], bm, acc, 0, 0, 0);
      acc = __builtin_amdgcn_mfma_f32_16x16x32_bf16(ah[ks], bl, acc, 0, 0, 0);
      acc = __builtin_amdgcn_mfma_f32_16x16x32_bf16(al[ks], bh, acc, 0, 0, 0);
    }
    int f = fl;
    if (f < F) {
      if (XW) {
        #pragma unroll
        for (int reg = 0; reg < 4; reg++) XW[(row0 + reg) * F + f] = acc[reg];
      }
      if (Yth) {
        float dvv[4] = {dv4.x, dv4.y, dv4.z, dv4.w};
        unsigned long long hpk = 0, lpk = 0;
        #pragma unroll
        for (int reg = 0; reg < 4; reg++) {
          float v = dvv[reg] * acc[reg];
          unsigned short hi = f2bf(v);
          unsigned short lo = f2bf(v - bf2f(hi));
          hpk |= ((unsigned long long)hi) << (16 * reg);
          lpk |= ((unsigned long long)lo) << (16 * reg);
        }
        long o = ytBase + ((long)f << nShift);
        *(unsigned long long*)(Yth + o) = hpk;
        *(unsigned long long*)(Ytl + o) = lpk;
      }
    }
  }
}

// ---------- LDS-free fused GCN: ITP it-tiles per wave (B-loads reused ITP×), A in regs ----------
// out[b,i,f] = relu?( d_i*(A@(Yh+Yl)) + 2 d_i*Y[f][i] + bias_f ),  Y[f][i] ≈ d_i*xw_if
// grid = (n/(64*ITP)) * BATCH; b = blockIdx&255 (same-batch blocks share an XCD)
template<int KS, int ITP>
__global__ __launch_bounds__(256) void k_gcn2(
    const unsigned short* __restrict__ Abf, const float* __restrict__ dinv,
    const unsigned short* __restrict__ Yth, const unsigned short* __restrict__ Ytl,
    const float* __restrict__ bias, float* __restrict__ out,
    int F, int Fpad, int dorelu) {
  constexpr int n = KS * 32;
  int b = blockIdx.x & (BATCH - 1);
  int sub = blockIdx.x >> 8;
  int wave = threadIdx.x >> 6, lane = threadIdx.x & 63;
  int r = lane & 15, q = lane >> 4;
  const float* dv = dinv + (size_t)b * n;
  int itBase = (sub * 4 + wave) * ITP;
  bf16x8_t af[ITP][KS];
  #pragma unroll
  for (int l = 0; l < ITP; l++) {
    const unsigned short* ap = Abf + ((size_t)b * n + (itBase + l) * 16 + r) * n + q * 8;
    #pragma unroll
    for (int ks = 0; ks < KS; ks++) af[l][ks] = *(const bf16x8_t*)(ap + ks * 32);
  }
  float di[ITP][4];
  #pragma unroll
  for (int l = 0; l < ITP; l++) {
    int i0 = (itBase + l) * 16 + q * 4;
    #pragma unroll
    for (int reg = 0; reg < 4; reg++) di[l][reg] = dv[i0 + reg];
  }
  int nFT = Fpad >> 4;
  for (int ft = 0; ft < nFT; ft++) {
    int fl = ft * 16 + r;
    const unsigned short* yrowh = Yth + ((size_t)b * Fpad + fl) * n;
    const unsigned short* yrowl = Ytl + ((size_t)b * Fpad + fl) * n;
    f32x4_t acc[ITP];
    #pragma unroll
    for (int l = 0; l < ITP; l++) acc[l] = (f32x4_t){0.f, 0.f, 0.f, 0.f};
    #pragma unroll
    for (int ks = 0; ks < KS; ks++) {
      bf16x8_t bh = *(const bf16x8_t*)(yrowh + q * 8 + ks * 32);
      bf16x8_t bl = *(const bf16x8_t*)(yrowl + q * 8 + ks * 32);
      #pragma unroll
      for (int l = 0; l < ITP; l++) {
        acc[l] = __builtin_amdgcn_mfma_f32_16x16x32_bf16(af[l][ks], bh, acc[l], 0, 0, 0);
        acc[l] = __builtin_amdgcn_mfma_f32_16x16x32_bf16(af[l][ks], bl, acc[l], 0, 0, 0);
      }
    }
    if (fl < F) {
      float bf = bias[fl];
      #pragma unroll
      for (int l = 0; l < ITP; l++) {
        int i0 = (itBase + l) * 16 + q * 4;
        unsigned long long hq = *(const unsigned long long*)(yrowh + i0);
        unsigned long long lq = *(const unsigned long long*)(yrowl + i0);
        #pragma unroll
        for (int reg = 0; reg < 4; reg++) {
          float yv = bf2f((unsigned short)(hq >> (16 * reg)))
                   + bf2f((unsigned short)(lq >> (16 * reg)));
          float v = di[l][reg] * acc[l][reg] + 2.f * di[l][reg] * yv + bf;
          if (dorelu) v = fmaxf(v, 0.f);
          out[((size_t)b * n + i0 + reg) * F + fl] = v;
        }
      }
    }
  }
}

// ---------- MFMA augment (EXACT integer arithmetic) ----------
__global__ __launch_bounds__(256) void k_aug_mfma(const unsigned short* __restrict__ Abf,
                                                  const int* __restrict__ perm,
                                                  float* __restrict__ Ap,
                                                  unsigned short* __restrict__ Apbf,
                                                  int n, int k, int nTiles) {
  int wid = (blockIdx.x * 256 + threadIdx.x) >> 6;
  if (wid >= nTiles) return;
  int lane = threadIdx.x & 63;
  int kt = k >> 4;
  int b = wid / (kt * kt);
  int rem = wid - b * (kt * kt);
  int it = rem / kt, ft = rem - it * kt;
  int r = lane & 15, q = lane >> 4;
  const int* pm = perm + (size_t)b * k;
  int rowA = pm[it * 16 + r];
  int rowB = pm[ft * 16 + r];
  const unsigned short* Ab = Abf + (size_t)b * n * n;
  const unsigned short* pa = Ab + (size_t)rowA * n + q * 8;
  const unsigned short* pb = Ab + (size_t)rowB * n + q * 8;
  f32x4_t acc = {0.f, 0.f, 0.f, 0.f};
  for (int k0 = 0; k0 < n; k0 += 32) {
    bf16x8_t a  = *(const bf16x8_t*)(pa + k0);
    bf16x8_t bv = *(const bf16x8_t*)(pb + k0);
    acc = __builtin_amdgcn_mfma_f32_16x16x32_bf16(a, bv, acc, 0, 0, 0);
  }
  int c = ft * 16 + r;
  const unsigned short* rowBp = Ab + (size_t)rowB * n;
  #pragma unroll
  for (int reg = 0; reg < 4; reg++) {
    int rr = it * 16 + q * 4 + reg;
    int pr = pm[rr];
    float v = acc[reg] + 2.f * bf2f(rowBp[pr]);
    if (rr == c) v = 0.f;
    if (Ap)   Ap[((size_t)b * k + rr) * k + c] = v;
    if (Apbf) Apbf[((size_t)b * k + rr) * k + c] = f2bf(v);
  }
}

// ---------- VALU augment for tiny levels ----------
__global__ __launch_bounds__(256) void k_aug(const float* __restrict__ A,
                                             const int* __restrict__ perm,
                                             float* __restrict__ Ap,
                                             int n, int k) {
  int b = blockIdx.y, r0 = blockIdx.x * 4, t = threadIdx.x;
  __shared__ float sR[4 * 256];
  __shared__ int spm[4];
  const float* Ab = A + (size_t)b * n * n;
  if (t < 4) spm[t] = perm[(size_t)b * k + r0 + t];
  __syncthreads();
  for (int idx = t; idx < 4 * n; idx += 256) {
    int rl = idx / n, j = idx - rl * n;
    sR[rl * n + j] = Ab[(size_t)spm[rl] * n + j];
  }
  __syncthreads();
  for (int c = t; c < k; c += 256) {
    int pc = perm[(size_t)b * k + c];
    const float* rowc = Ab + (size_t)pc * n;
    float a0 = 0.f, a1 = 0.f, a2 = 0.f, a3 = 0.f;
    for (int j = 0; j < n; j++) {
      float v = rowc[j];
      a0 += sR[j] * v;
      a1 += sR[n + j] * v;
      a2 += sR[2 * n + j] * v;
      a3 += sR[3 * n + j] * v;
    }
    float accs[4] = {a0, a1, a2, a3};
    for (int rl = 0; rl < 4; rl++) {
      int r = r0 + rl;
      float res = accs[rl] + 2.f * Ab[(size_t)spm[rl] * n + pc];
      Ap[((size_t)b * k + r) * k + c] = (r == c) ? 0.f : res;
    }
  }
}

// ---------- VALU anxw for small n ----------
__global__ __launch_bounds__(256) void k_anxw(const float* __restrict__ A,
                                              const float* __restrict__ dinv,
                                              const float* __restrict__ xw,
                                              const float* __restrict__ bias,
                                              float* __restrict__ out,
                                              int n, int F, int dorelu) {
  int b = blockIdx.y, i0 = blockIdx.x * 4, t = threadIdx.x;
  __shared__ float sA[4 * 256];
  const float* Ab = A + (size_t)b * n * n;
  const float* dv = dinv + (size_t)b * n;
  for (int idx = t; idx < 4 * n; idx += 256) {
    int il = idx / n, j = idx - il * n;
    sA[il * n + j] = Ab[(size_t)(i0 + il) * n + j] * dv[j];
  }
  __syncthreads();
  const float* xwb = xw + (size_t)b * n * F;
  for (int idx = t; idx < 4 * F; idx += 256) {
    int il = idx / F, f = idx - il * F;
    int i = i0 + il;
    const float* sr = &sA[il * n];
    float acc = 0.f;
    for (int j = 0; j < n; j++) acc += sr[j] * xwb[(size_t)j * F + f];
    float di = dv[i];
    float v = di * acc + 2.f * di * di * xwb[(size_t)i * F + f] + bias[f];
    if (dorelu) v = fmaxf(v, 0.f);
    out[((size_t)b * n + i) * F + f] = v;
  }
}

// ---------- fused pooling: score + exact top-k rank + gather ----------
__global__ __launch_bounds__(256) void k_pool(const float* __restrict__ H,
                                              const float* __restrict__ p,
                                              int* __restrict__ perm,
                                              float* __restrict__ Hout,
                                              int n, int k) {
  int b = blockIdx.x, t = threadIdx.x;
  __shared__ float s[256];
  __shared__ int sord[128];
  float pn = 0.f;
  #pragma unroll
  for (int j = 0; j < HID; j++) pn += p[j] * p[j];
  if (t < n) {
    const float* hr = H + ((size_t)b * n + t) * HID;
    float acc = 0.f;
    #pragma unroll
    for (int j = 0; j < HID; j++) acc += hr[j] * p[j];
    s[t] = tanhf(acc / sqrtf(pn));
  }
  __syncthreads();
  if (t < n) {
    float v = s[t];
    int r = 0;
    for (int j = 0; j < n; j++) {
      float u = s[j];
      r += (u > v) || (u == v && j < t);
    }
    if (r < k) { perm[(size_t)b * k + r] = t; sord[r] = t; }
  }
  __syncthreads();
  for (int idx = t; idx < k * HID; idx += 256) {
    int r = idx / HID, f = idx - r * HID;
    int pi = sord[r];
    Hout[((size_t)b * k + r) * HID + f] = H[((size_t)b * n + pi) * HID + f] * s[pi];
  }
}

// ---------- decoder scatter-add ----------
__global__ __launch_bounds__(256) void k_scatter(const int* __restrict__ perm,
                                                 const float* __restrict__ Hsrc,
                                                 float* __restrict__ Hdst,
                                                 int n, int k, int total) {
  int idx = blockIdx.x * 256 + threadIdx.x;
  if (idx >= total) return;
  int f = idx % HID;
  int r = (idx / HID) % k;
  int b = idx / (HID * k);
  int pi = perm[(size_t)b * k + r];
  Hdst[((size_t)b * n + pi) * HID + f] += Hsrc[idx];
}

// ---------- fused head ----------
__global__ __launch_bounds__(256) void k_head(const float* __restrict__ HT,
                                              const float* __restrict__ c1W,
                                              const float* __restrict__ c1b,
                                              const float* __restrict__ c2W,
                                              const float* __restrict__ c2b,
                                              const float* __restrict__ oW,
                                              const float* __restrict__ ob,
                                              float* __restrict__ out) {
  int b = blockIdx.x, t = threadIdx.x;
  __shared__ float sc[256];
  __shared__ int ord[30];
  __shared__ float sp[30 * 97];
  __shared__ float y1[16 * 30];
  __shared__ float yp[16 * 15];
  __shared__ float yc[32 * 11];
  const float* Hb = HT + (size_t)b * NNODE * DOUT;
  sc[t] = Hb[(size_t)t * DOUT + (DOUT - 1)];
  __syncthreads();
  {
    float v = sc[t];
    int r = 0;
    for (int j = 0; j < 256; j++) {
      float u = sc[j];
      r += (u > v) || (u == v && j < t);
    }
    if (r < 30) ord[r] = t;
  }
  __syncthreads();
  for (int idx = t; idx < 30 * 97; idx += 256) {
    int r = idx / 97, d = idx - r * 97;
    sp[idx] = Hb[(size_t)ord[r] * DOUT + d];
  }
  __syncthreads();
  for (int idx = t; idx < 16 * 30; idx += 256) {
    int c = idx / 30, kk = idx - c * 30;
    float a = c1b[c];
    for (int d = 0; d < 97; d++) a += sp[kk * 97 + d] * c1W[c * 97 + d];
    y1[c * 30 + kk] = fmaxf(a, 0.f);
  }
  __syncthreads();
  for (int idx = t; idx < 16 * 15; idx += 256) {
    int c = idx / 15, t2 = idx - c * 15;
    yp[idx] = fmaxf(y1[c * 30 + 2 * t2], y1[c * 30 + 2 * t2 + 1]);
  }
  __syncthreads();
  for (int idx = t; idx < 32 * 11; idx += 256) {
    int o = idx / 11, t3 = idx - o * 11;
    float a = c2b[o];
    for (int i2 = 0; i2 < 16; i2++)
      for (int w = 0; w < 5; w++)
        a += yp[i2 * 15 + t3 + w] * c2W[(o * 16 + i2) * 5 + w];
    yc[o * 11 + t3] = fmaxf(a, 0.f);
  }
  __syncthreads();
  if (t < 32) {
    float a = ob[t];
    for (int q = 0; q < 352; q++) a += yc[q] * oW[q * 32 + t];
    out[(size_t)b * 32 + t] = fmaxf(a, 0.f);
  }
}

extern "C" void kernel_launch(void* const* d_in, const int* in_sizes, int n_in,
                              void* d_out, int out_size, void* d_ws, size_t ws_size,
                              hipStream_t stream) {
  const float* x   = (const float*)d_in[0];
  const float* A0  = (const float*)d_in[1];
  const float* dW0 = (const float*)d_in[2];
  const float* db0 = (const float*)d_in[3];
  const float* dW  = (const float*)d_in[4];
  const float* dbv = (const float*)d_in[5];
  const float* pp  = (const float*)d_in[6];
  const float* uW  = (const float*)d_in[7];
  const float* ub  = (const float*)d_in[8];
  const float* uWl = (const float*)d_in[9];
  const float* ubl = (const float*)d_in[10];
  const float* c1W = (const float*)d_in[11];
  const float* c1b = (const float*)d_in[12];
  const float* c2W = (const float*)d_in[13];
  const float* c2b = (const float*)d_in[14];
  const float* oW  = (const float*)d_in[15];
  const float* ob  = (const float*)d_in[16];
  float* out = (float*)d_out;

  float* base = (float*)d_ws;
  size_t off = 0;
  auto alloc = [&](size_t nel) { nel = (nel + 3) & ~(size_t)3; float* p = base + off; off += nel; return p; };
  float* H0 = alloc((size_t)BATCH * 256 * HID);
  float* H1 = alloc((size_t)BATCH * 128 * HID);
  float* H2 = alloc((size_t)BATCH * 64 * HID);
  float* H3 = alloc((size_t)BATCH * 32 * HID);
  float* H4 = alloc((size_t)BATCH * 16 * HID);
  float* HT = alloc((size_t)BATCH * 256 * DOUT);
  float* XW = alloc((size_t)BATCH * 256 * DOUT);
  float* A2 = alloc((size_t)BATCH * 64 * 64);
  float* A3 = alloc((size_t)BATCH * 32 * 32);
  float* A4 = alloc((size_t)BATCH * 16 * 16);
  float* D0 = alloc((size_t)BATCH * 256);
  float* D1 = alloc((size_t)BATCH * 128);
  float* D2 = alloc((size_t)BATCH * 64);
  float* D3 = alloc((size_t)BATCH * 32);
  float* D4 = alloc((size_t)BATCH * 16);
  int* P1 = (int*)alloc((size_t)BATCH * 128);
  int* P2 = (int*)alloc((size_t)BATCH * 64);
  int* P3 = (int*)alloc((size_t)BATCH * 32);
  int* P4 = (int*)alloc((size_t)BATCH * 16);
  unsigned short* Abf0 = (unsigned short*)alloc((size_t)BATCH * 256 * 256 / 2);
  unsigned short* Abf1 = (unsigned short*)alloc((size_t)BATCH * 128 * 128 / 2);
  unsigned short* Yth  = (unsigned short*)alloc((size_t)BATCH * 112 * 256 / 2);
  unsigned short* Ytl  = (unsigned short*)alloc((size_t)BATCH * 112 * 256 / 2);
  unsigned short* Wp   = (unsigned short*)alloc((size_t)3 * WTOT / 2 + 4);

  int ns[5] = {256, 128, 64, 32, 16};
  float* Hl[5] = {H0, H1, H2, H3, H4};
  float* Al[5] = {nullptr, nullptr, A2, A3, A4};
  float* Dl[5] = {D0, D1, D2, D3, D4};
  int* Pl[4] = {P1, P2, P3, P4};

  // ---- prologue ----
  k_prepA<<<BATCH * 256 / 4, 256, 0, stream>>>(A0, Abf0, D0, BATCH * 256);
  k_splitW3<<<(WTOT + 255) / 256, 256, 0, stream>>>(dW0, dW, uW, uWl, Wp);

  // ---- first GCN: xws (Yt only, no XW), gcn2 ITP=2 ----
  {
    k_xws<4><<<BATCH * 256 / 64, 256, 0, stream>>>(x, Wp + WOFF_DW0, nullptr,
                                                   D0, Yth, Ytl, FIN, HID, 48, 8);
    k_gcn2<8, 2><<<BATCH * 2, 256, 0, stream>>>(Abf0, D0, Yth, Ytl, db0, H0, HID, 48, 1);
  }

  // ---- encoder levels ----
  for (int i = 0; i < 4; i++) {
    int n = ns[i], kk = ns[i + 1];
    k_pool<<<BATCH, 256, 0, stream>>>(Hl[i], pp + i * HID, Pl[i], Hl[i + 1], n, kk);
    if (i == 0) {
      int nT = BATCH * 8 * 8;
      k_aug_mfma<<<(nT + 3) / 4, 256, 0, stream>>>(Abf0, P1, nullptr, Abf1, 256, 128, nT);
      k_dinv_bf<<<BATCH * 128 / 4, 256, 0, stream>>>(Abf1, D1, 128, BATCH * 128);
    } else if (i == 1) {
      int nT = BATCH * 4 * 4;
      k_aug_mfma<<<(nT + 3) / 4, 256, 0, stream>>>(Abf1, P2, A2, nullptr, 128, 64, nT);
      k_dinv<<<BATCH * 64 / 4, 256, 0, stream>>>(A2, D2, 64, BATCH * 64);
    } else {
      k_aug<<<dim3(kk / 4, BATCH), 256, 0, stream>>>(Al[i], Pl[i], Al[i + 1], n, kk);
      k_dinv<<<(BATCH * kk + 3) / 4, 256, 0, stream>>>(Al[i + 1], Dl[i + 1], kk, BATCH * kk);
    }
    if (kk == 128) {
      k_xws<2><<<BATCH * kk / 64, 256, 0, stream>>>(Hl[i + 1], Wp + WOFF_DW + i * 3072,
                                                    nullptr, D1, Yth, Ytl, HID, HID, 48, 7);
      k_gcn2<4, 1><<<BATCH * 2, 256, 0, stream>>>(Abf1, D1, Yth, Ytl, dbv + i * HID,
                                                  Hl[i + 1], HID, 48, 1);
    } else {
      k_xws<2><<<BATCH * kk / 64, 256, 0, stream>>>(Hl[i + 1], Wp + WOFF_DW + i * 3072,
                                                    XW, nullptr, nullptr, nullptr,
                                                    HID, HID, 48, 0);
      k_anxw<<<dim3(kk / 4, BATCH), 256, 0, stream>>>(Al[i + 1], Dl[i + 1], XW,
                                                      dbv + i * HID, Hl[i + 1], kk, HID, 1);
    }
  }

  // ---- decoder ----
  for (int i = 0; i < 4; i++) {
    int j = 3 - i, nj = ns[j], kj = ns[j + 1];
    k_scatter<<<(BATCH * kj * HID + 255) / 256, 256, 0, stream>>>(Pl[j], Hl[j + 1], Hl[j],
                                                                  nj, kj, BATCH * kj * HID);
    if (i < 3) {
      if (nj == 128) {
        k_xws<2><<<BATCH * nj / 64, 256, 0, stream>>>(Hl[j], Wp + WOFF_UW + i * 3072,
                                                      nullptr, D1, Yth, Ytl, HID, HID, 48, 7);
        k_gcn2<4, 1><<<BATCH * 2, 256, 0, stream>>>(Abf1, D1, Yth, Ytl, ub + i * HID,
                                                    Hl[j], HID, 48, 1);
      } else {
        k_xws<2><<<BATCH * nj / 64, 256, 0, stream>>>(Hl[j], Wp + WOFF_UW + i * 3072,
                                                      XW, nullptr, nullptr, nullptr,
                                                      HID, HID, 48, 0);
        k_anxw<<<dim3(nj / 4, BATCH), 256, 0, stream>>>(Al[j], Dl[j], XW, ub + i * HID,
                                                        Hl[j], nj, HID, 1);
      }
    } else {
      k_xws<2><<<BATCH * 256 / 64, 256, 0, stream>>>(H0, Wp + WOFF_UWL, nullptr,
                                                     D0, Yth, Ytl, HID, DOUT, 112, 8);
      k_gcn2<8, 2><<<BATCH * 2, 256, 0, stream>>>(Abf0, D0, Yth, Ytl, ubl, HT, DOUT, 112, 0);
    }
  }

  // ---- fused head ----
  k_head<<<BATCH, 256, 0, stream>>>(HT, c1W, c1b, c2W, c2b, oW, ob, out);
}

// Round 12
// 541.736 us; speedup vs baseline: 1.0572x; 1.0075x over previous
//
#include <hip/hip_runtime.h>
#include <math.h>

#define BATCH 256
#define NNODE 256
#define FIN   128
#define HID   48
#define DOUT  97

// packed transposed weight planes (ushort elements, per-plane offsets)
#define WOFF_DW0 0        // dW0^T [48][128]
#define WOFF_DW  6144     // dW[i]^T 4 x [48][64]
#define WOFF_UW  18432    // uW[i]^T 3 x [48][64]
#define WOFF_UWL 27648    // uWl^T  [112][64]
#define WTOT     34816    // per-plane stride

typedef __attribute__((ext_vector_type(8))) short bf16x8_t;
typedef __attribute__((ext_vector_type(4))) float f32x4_t;

__device__ inline unsigned short f2bf(float x) {
  unsigned u = __float_as_uint(x);
  u += 0x7fff + ((u >> 16) & 1);
  return (unsigned short)(u >> 16);
}
__device__ inline float bf2f(unsigned short h) {
  return __uint_as_float(((unsigned)h) << 16);
}

// ---------- fused A0 pass: bf16 convert + rowsum -> dinv (exact: 0/1 entries) ----------
__global__ __launch_bounds__(256) void k_prepA(const float* __restrict__ A,
                                               unsigned short* __restrict__ Abf,
                                               float* __restrict__ dinv, int rows) {
  int wid = (blockIdx.x * 256 + threadIdx.x) >> 6;
  int lane = threadIdx.x & 63;
  if (wid >= rows) return;
  const float4* rp = (const float4*)(A + (size_t)wid * 256);
  float4 v = rp[lane];
  unsigned long long pk = (unsigned long long)f2bf(v.x)
                        | ((unsigned long long)f2bf(v.y) << 16)
                        | ((unsigned long long)f2bf(v.z) << 32)
                        | ((unsigned long long)f2bf(v.w) << 48);
  *(unsigned long long*)(Abf + (size_t)wid * 256 + lane * 4) = pk;
  float s = v.x + v.y + v.z + v.w;
  #pragma unroll
  for (int o = 32; o > 0; o >>= 1) s += __shfl_down(s, o);
  if (lane == 0) dinv[wid] = 1.0f / sqrtf(s + 2.0f);
}

// ---------- dinv from bf16 integer adjacency (exact) ----------
__global__ __launch_bounds__(256) void k_dinv_bf(const unsigned short* __restrict__ Abf,
                                                 float* __restrict__ dinv, int n, int rows) {
  int wid = (blockIdx.x * 256 + threadIdx.x) >> 6;
  int lane = threadIdx.x & 63;
  if (wid >= rows) return;
  const unsigned short* row = Abf + (size_t)wid * n;
  float s = 0.f;
  for (int j = lane * 2; j < n; j += 128) {
    unsigned u = *(const unsigned*)(row + j);
    s += bf2f((unsigned short)(u & 0xffffu)) + bf2f((unsigned short)(u >> 16));
  }
  #pragma unroll
  for (int o = 32; o > 0; o >>= 1) s += __shfl_down(s, o);
  if (lane == 0) dinv[wid] = 1.0f / sqrtf(s + 2.0f);
}

// ---------- rowsum -> dinv (fp32 A, deeper levels) ----------
__global__ __launch_bounds__(256) void k_dinv(const float* __restrict__ A,
                                              float* __restrict__ dinv,
                                              int n, int rows) {
  int wid  = (blockIdx.x * blockDim.x + threadIdx.x) >> 6;
  int lane = threadIdx.x & 63;
  if (wid >= rows) return;
  const float* row = A + (size_t)wid * n;
  float s = 0.f;
  for (int j = lane; j < n; j += 64) s += row[j];
  #pragma unroll
  for (int o = 32; o > 0; o >>= 1) s += __shfl_down(s, o);
  if (lane == 0) dinv[wid] = 1.0f / sqrtf(s + 2.0f);
}

// ---------- transpose + 3-plane split ALL weights (runs once, tiny) ----------
__global__ __launch_bounds__(256) void k_splitW3(const float* __restrict__ dW0,
                                                 const float* __restrict__ dW,
                                                 const float* __restrict__ uW,
                                                 const float* __restrict__ uWl,
                                                 unsigned short* __restrict__ Wp) {
  int idx = blockIdx.x * 256 + threadIdx.x;
  if (idx >= WTOT) return;
  float v;
  if (idx < WOFF_DW) {                   // dW0^T [48][128]
    int f = idx / 128, kk = idx - f * 128;
    v = dW0[kk * HID + f];
  } else if (idx < WOFF_UW) {            // dW[i]^T [48][64]
    int r = idx - WOFF_DW;
    int i = r / 3072; r -= i * 3072;
    int f = r / 64, kk = r - f * 64;
    v = (kk < HID) ? dW[((size_t)i * HID + kk) * HID + f] : 0.f;
  } else if (idx < WOFF_UWL) {           // uW[i]^T [48][64]
    int r = idx - WOFF_UW;
    int i = r / 3072; r -= i * 3072;
    int f = r / 64, kk = r - f * 64;
    v = (kk < HID) ? uW[((size_t)i * HID + kk) * HID + f] : 0.f;
  } else {                               // uWl^T [112][64]
    int r = idx - WOFF_UWL;
    int f = r / 64, kk = r - f * 64;
    v = (f < DOUT && kk < HID) ? uWl[(size_t)kk * DOUT + f] : 0.f;
  }
  unsigned short h = f2bf(v);
  float r1 = v - bf2f(h);
  unsigned short m = f2bf(r1);
  float r2 = r1 - bf2f(m);
  unsigned short l = f2bf(r2);
  Wp[idx] = h;
  Wp[idx + WTOT] = m;
  Wp[idx + 2 * WTOT] = l;
}

// ---------- wave-independent MFMA GEMM XW = X @ W, 3-plane split, NO LDS/barrier ----------
template<int KS2>   // K-steps of 32; KP = KS2*32
__global__ __launch_bounds__(256) void k_xws(const float* __restrict__ X,
                                             const unsigned short* __restrict__ Wp,
                                             float* __restrict__ XW,
                                             const float* __restrict__ dinv,
                                             unsigned short* __restrict__ Yth,
                                             unsigned short* __restrict__ Ytl,
                                             int K, int F, int Fpad, int nShift) {
  constexpr int KP = KS2 * 32;
  int mt = (blockIdx.x * 256 + threadIdx.x) >> 6;
  int lane = threadIdx.x & 63;
  int r = lane & 15, q = lane >> 4;
  const float* xr = X + ((long)mt * 16 + r) * K;
  bf16x8_t ah[KS2], am[KS2], al[KS2];
  #pragma unroll
  for (int ks = 0; ks < KS2; ks++) {
    int col0 = ks * 32 + q * 8;
    float v[8];
    if (col0 + 8 <= K) {
      float4 a = *(const float4*)(xr + col0);
      float4 b = *(const float4*)(xr + col0 + 4);
      v[0] = a.x; v[1] = a.y; v[2] = a.z; v[3] = a.w;
      v[4] = b.x; v[5] = b.y; v[6] = b.z; v[7] = b.w;
    } else {
      #pragma unroll
      for (int j = 0; j < 8; j++) v[j] = (col0 + j < K) ? xr[col0 + j] : 0.f;
    }
    #pragma unroll
    for (int j = 0; j < 8; j++) {
      unsigned short h = f2bf(v[j]);
      float r1 = v[j] - bf2f(h);
      unsigned short m = f2bf(r1);
      float r2 = r1 - bf2f(m);
      unsigned short l = f2bf(r2);
      ah[ks][j] = (short)h;
      am[ks][j] = (short)m;
      al[ks][j] = (short)l;
    }
  }
  long row0 = (long)mt * 16 + q * 4;
  float4 dv4 = {0.f, 0.f, 0.f, 0.f};
  long ytBase = 0;
  if (Yth) {
    dv4 = *(const float4*)(dinv + row0);
    int bb = (int)(row0 >> nShift);
    int jj = (int)(row0 & ((1 << nShift) - 1));
    ytBase = (long)bb * Fpad;
    ytBase = ytBase << nShift;
    ytBase += jj;
  }
  int nFT = Fpad >> 4;
  for (int ft = 0; ft < nFT; ft++) {
    int fl = ft * 16 + r;
    const unsigned short* wb = Wp + (size_t)fl * KP + q * 8;
    f32x4_t acc = {0.f, 0.f, 0.f, 0.f};
    #pragma unroll
    for (int ks = 0; ks < KS2; ks++) {
      bf16x8_t bh = *(const bf16x8_t*)(wb + ks * 32);
      bf16x8_t bm = *(const bf16x8_t*)(wb + WTOT + ks * 32);
      bf16x8_t bl = *(const bf16x8_t*)(wb + 2 * WTOT + ks * 32);
      acc = __builtin_amdgcn_mfma_f32_16x16x32_bf16(ah[ks], bh, acc, 0, 0, 0);
      acc = __builtin_amdgcn_mfma_f32_16x16x32_bf16(ah[ks], bm, acc, 0, 0, 0);
      acc = __builtin_amdgcn_mfma_f32_16x16x32_bf16(am[ks], bh, acc, 0, 0, 0);
      acc = __builtin_amdgcn_mfma_f32_16x16x32_bf16(am[ks], bm, acc, 0, 0, 0);
      acc = __builtin_amdgcn_mfma_f32_16x16x32_bf16(ah[ks], bl, acc, 0, 0, 0);
      acc = __builtin_amdgcn_mfma_f32_16x16x32_bf16(al[ks], bh, acc, 0, 0, 0);
    }
    int f = fl;
    if (f < F) {
      if (XW) {
        #pragma unroll
        for (int reg = 0; reg < 4; reg++) XW[(row0 + reg) * F + f] = acc[reg];
      }
      if (Yth) {
        float dvv[4] = {dv4.x, dv4.y, dv4.z, dv4.w};
        unsigned long long hpk = 0, lpk = 0;
        #pragma unroll
        for (int reg = 0; reg < 4; reg++) {
          float v = dvv[reg] * acc[reg];
          unsigned short hi = f2bf(v);
          unsigned short lo = f2bf(v - bf2f(hi));
          hpk |= ((unsigned long long)hi) << (16 * reg);
          lpk |= ((unsigned long long)lo) << (16 * reg);
        }
        long o = ytBase + ((long)f << nShift);
        *(unsigned long long*)(Yth + o) = hpk;
        *(unsigned long long*)(Ytl + o) = lpk;
      }
    }
  }
}

// ---------- LDS-free fused GCN: ITP it-tiles per wave, A in regs ----------
template<int KS, int ITP>
__global__ __launch_bounds__(256) void k_gcn2(
    const unsigned short* __restrict__ Abf, const float* __restrict__ dinv,
    const unsigned short* __restrict__ Yth, const unsigned short* __restrict__ Ytl,
    const float* __restrict__ bias, float* __restrict__ out,
    int F, int Fpad, int dorelu) {
  constexpr int n = KS * 32;
  int b = blockIdx.x & (BATCH - 1);
  int sub = blockIdx.x >> 8;
  int wave = threadIdx.x >> 6, lane = threadIdx.x & 63;
  int r = lane & 15, q = lane >> 4;
  const float* dv = dinv + (size_t)b * n;
  int itBase = (sub * 4 + wave) * ITP;
  bf16x8_t af[ITP][KS];
  #pragma unroll
  for (int l = 0; l < ITP; l++) {
    const unsigned short* ap = Abf + ((size_t)b * n + (itBase + l) * 16 + r) * n + q * 8;
    #pragma unroll
    for (int ks = 0; ks < KS; ks++) af[l][ks] = *(const bf16x8_t*)(ap + ks * 32);
  }
  float di[ITP][4];
  #pragma unroll
  for (int l = 0; l < ITP; l++) {
    int i0 = (itBase + l) * 16 + q * 4;
    #pragma unroll
    for (int reg = 0; reg < 4; reg++) di[l][reg] = dv[i0 + reg];
  }
  int nFT = Fpad >> 4;
  for (int ft = 0; ft < nFT; ft++) {
    int fl = ft * 16 + r;
    const unsigned short* yrowh = Yth + ((size_t)b * Fpad + fl) * n;
    const unsigned short* yrowl = Ytl + ((size_t)b * Fpad + fl) * n;
    f32x4_t acc[ITP];
    #pragma unroll
    for (int l = 0; l < ITP; l++) acc[l] = (f32x4_t){0.f, 0.f, 0.f, 0.f};
    #pragma unroll
    for (int ks = 0; ks < KS; ks++) {
      bf16x8_t bh = *(const bf16x8_t*)(yrowh + q * 8 + ks * 32);
      bf16x8_t bl = *(const bf16x8_t*)(yrowl + q * 8 + ks * 32);
      #pragma unroll
      for (int l = 0; l < ITP; l++) {
        acc[l] = __builtin_amdgcn_mfma_f32_16x16x32_bf16(af[l][ks], bh, acc[l], 0, 0, 0);
        acc[l] = __builtin_amdgcn_mfma_f32_16x16x32_bf16(af[l][ks], bl, acc[l], 0, 0, 0);
      }
    }
    if (fl < F) {
      float bf = bias[fl];
      #pragma unroll
      for (int l = 0; l < ITP; l++) {
        int i0 = (itBase + l) * 16 + q * 4;
        unsigned long long hq = *(const unsigned long long*)(yrowh + i0);
        unsigned long long lq = *(const unsigned long long*)(yrowl + i0);
        #pragma unroll
        for (int reg = 0; reg < 4; reg++) {
          float yv = bf2f((unsigned short)(hq >> (16 * reg)))
                   + bf2f((unsigned short)(lq >> (16 * reg)));
          float v = di[l][reg] * acc[l][reg] + 2.f * di[l][reg] * yv + bf;
          if (dorelu) v = fmaxf(v, 0.f);
          out[((size_t)b * n + i0 + reg) * F + fl] = v;
        }
      }
    }
  }
}

// ---------- final-GCN column 96 (ranking scores): matvec per node ----------
// col[b,i] = d_i * sum_j A[b,i,j]*(Yh96[j]+Yl96[j]) + 2*d_i*(Yh96[i]+Yl96[i])
// (bias ubl[96] omitted: constant shift, rank-invariant)
__global__ __launch_bounds__(256) void k_hcol(const unsigned short* __restrict__ Abf,
                                              const float* __restrict__ dinv,
                                              const unsigned short* __restrict__ Yth,
                                              const unsigned short* __restrict__ Ytl,
                                              float* __restrict__ col) {
  int gw = blockIdx.x * 4 + (threadIdx.x >> 6);   // gw = b*256 + i
  int lane = threadIdx.x & 63;
  int b = gw >> 8, i = gw & 255;
  const unsigned short* ar = Abf + (size_t)gw * 256;
  const unsigned short* yh = Yth + ((size_t)b * 112 + 96) * 256;
  const unsigned short* yl = Ytl + ((size_t)b * 112 + 96) * 256;
  unsigned long long a4 = *(const unsigned long long*)(ar + lane * 4);
  unsigned long long h4 = *(const unsigned long long*)(yh + lane * 4);
  unsigned long long l4 = *(const unsigned long long*)(yl + lane * 4);
  float s = 0.f;
  #pragma unroll
  for (int e = 0; e < 4; e++) {
    float av = bf2f((unsigned short)(a4 >> (16 * e)));
    float yv = bf2f((unsigned short)(h4 >> (16 * e)))
             + bf2f((unsigned short)(l4 >> (16 * e)));
    s += av * yv;
  }
  #pragma unroll
  for (int o = 32; o > 0; o >>= 1) s += __shfl_down(s, o);
  if (lane == 0) {
    float d = dinv[gw];
    float yv = bf2f(yh[i]) + bf2f(yl[i]);
    col[gw] = d * s + 2.f * d * yv;
  }
}

// ---------- exact top-30 rank over col-96 scores ----------
__global__ __launch_bounds__(256) void k_hsel(const float* __restrict__ col,
                                              int* __restrict__ ord) {
  int b = blockIdx.x, t = threadIdx.x;
  __shared__ float s[256];
  s[t] = col[(size_t)b * 256 + t];
  __syncthreads();
  float v = s[t];
  int r = 0;
  for (int j = 0; j < 256; j++) {
    float u = s[j];
    r += (u > v) || (u == v && j < t);
  }
  if (r < 30) ord[(size_t)b * 30 + r] = t;
}

// ---------- final-GCN rows for top-30 nodes only (gathered-A MFMA) ----------
// sp[b,rowidx,f] = d_node*(A[node,:]@(Yh+Yl)[:,f]) + 2*d_node*Y[f][node] + ubl[f]
// wave = (it in {0,1}) x (ft-half in {0,1}); grid = BATCH
__global__ __launch_bounds__(256) void k_hrow(const unsigned short* __restrict__ Abf,
                                              const float* __restrict__ dinv,
                                              const int* __restrict__ ord,
                                              const unsigned short* __restrict__ Yth,
                                              const unsigned short* __restrict__ Ytl,
                                              const float* __restrict__ ubl,
                                              float* __restrict__ sp) {
  int b = blockIdx.x;
  int wave = threadIdx.x >> 6, lane = threadIdx.x & 63;
  int it = wave & 1, fh = wave >> 1;
  int r = lane & 15, q = lane >> 4;
  const int* po = ord + (size_t)b * 30;
  int ari = it * 16 + r;
  int arow = po[ari < 30 ? ari : 0];
  const unsigned short* ap = Abf + ((size_t)b * 256 + arow) * 256 + q * 8;
  bf16x8_t af[8];
  #pragma unroll
  for (int ks = 0; ks < 8; ks++) af[ks] = *(const bf16x8_t*)(ap + ks * 32);
  int ftBeg = fh * 4, ftEnd = fh ? 7 : 4;
  for (int ft = ftBeg; ft < ftEnd; ft++) {
    int fl = ft * 16 + r;
    const unsigned short* yrowh = Yth + ((size_t)b * 112 + fl) * 256;
    const unsigned short* yrowl = Ytl + ((size_t)b * 112 + fl) * 256;
    f32x4_t acc = {0.f, 0.f, 0.f, 0.f};
    #pragma unroll
    for (int ks = 0; ks < 8; ks++) {
      bf16x8_t bh = *(const bf16x8_t*)(yrowh + q * 8 + ks * 32);
      bf16x8_t bl = *(const bf16x8_t*)(yrowl + q * 8 + ks * 32);
      acc = __builtin_amdgcn_mfma_f32_16x16x32_bf16(af[ks], bh, acc, 0, 0, 0);
      acc = __builtin_amdgcn_mfma_f32_16x16x32_bf16(af[ks], bl, acc, 0, 0, 0);
    }
    if (fl < DOUT) {
      float bf = ubl[fl];
      #pragma unroll
      for (int reg = 0; reg < 4; reg++) {
        int rowidx = it * 16 + q * 4 + reg;
        if (rowidx < 30) {
          int node = po[rowidx];
          float d = dinv[(size_t)b * 256 + node];
          float yv = bf2f(yrowh[node]) + bf2f(yrowl[node]);
          sp[((size_t)b * 30 + rowidx) * DOUT + fl] = d * acc[reg] + 2.f * d * yv + bf;
        }
      }
    }
  }
}

// ---------- MFMA augment (EXACT integer arithmetic) ----------
__global__ __launch_bounds__(256) void k_aug_mfma(const unsigned short* __restrict__ Abf,
                                                  const int* __restrict__ perm,
                                                  float* __restrict__ Ap,
                                                  unsigned short* __restrict__ Apbf,
                                                  int n, int k, int nTiles) {
  int wid = (blockIdx.x * 256 + threadIdx.x) >> 6;
  if (wid >= nTiles) return;
  int lane = threadIdx.x & 63;
  int kt = k >> 4;
  int b = wid / (kt * kt);
  int rem = wid - b * (kt * kt);
  int it = rem / kt, ft = rem - it * kt;
  int r = lane & 15, q = lane >> 4;
  const int* pm = perm + (size_t)b * k;
  int rowA = pm[it * 16 + r];
  int rowB = pm[ft * 16 + r];
  const unsigned short* Ab = Abf + (size_t)b * n * n;
  const unsigned short* pa = Ab + (size_t)rowA * n + q * 8;
  const unsigned short* pb = Ab + (size_t)rowB * n + q * 8;
  f32x4_t acc = {0.f, 0.f, 0.f, 0.f};
  for (int k0 = 0; k0 < n; k0 += 32) {
    bf16x8_t a  = *(const bf16x8_t*)(pa + k0);
    bf16x8_t bv = *(const bf16x8_t*)(pb + k0);
    acc = __builtin_amdgcn_mfma_f32_16x16x32_bf16(a, bv, acc, 0, 0, 0);
  }
  int c = ft * 16 + r;
  const unsigned short* rowBp = Ab + (size_t)rowB * n;
  #pragma unroll
  for (int reg = 0; reg < 4; reg++) {
    int rr = it * 16 + q * 4 + reg;
    int pr = pm[rr];
    float v = acc[reg] + 2.f * bf2f(rowBp[pr]);
    if (rr == c) v = 0.f;
    if (Ap)   Ap[((size_t)b * k + rr) * k + c] = v;
    if (Apbf) Apbf[((size_t)b * k + rr) * k + c] = f2bf(v);
  }
}

// ---------- VALU augment for tiny levels ----------
__global__ __launch_bounds__(256) void k_aug(const float* __restrict__ A,
                                             const int* __restrict__ perm,
                                             float* __restrict__ Ap,
                                             int n, int k) {
  int b = blockIdx.y, r0 = blockIdx.x * 4, t = threadIdx.x;
  __shared__ float sR[4 * 256];
  __shared__ int spm[4];
  const float* Ab = A + (size_t)b * n * n;
  if (t < 4) spm[t] = perm[(size_t)b * k + r0 + t];
  __syncthreads();
  for (int idx = t; idx < 4 * n; idx += 256) {
    int rl = idx / n, j = idx - rl * n;
    sR[rl * n + j] = Ab[(size_t)spm[rl] * n + j];
  }
  __syncthreads();
  for (int c = t; c < k; c += 256) {
    int pc = perm[(size_t)b * k + c];
    const float* rowc = Ab + (size_t)pc * n;
    float a0 = 0.f, a1 = 0.f, a2 = 0.f, a3 = 0.f;
    for (int j = 0; j < n; j++) {
      float v = rowc[j];
      a0 += sR[j] * v;
      a1 += sR[n + j] * v;
      a2 += sR[2 * n + j] * v;
      a3 += sR[3 * n + j] * v;
    }
    float accs[4] = {a0, a1, a2, a3};
    for (int rl = 0; rl < 4; rl++) {
      int r = r0 + rl;
      float res = accs[rl] + 2.f * Ab[(size_t)spm[rl] * n + pc];
      Ap[((size_t)b * k + r) * k + c] = (r == c) ? 0.f : res;
    }
  }
}

// ---------- VALU anxw for small n ----------
__global__ __launch_bounds__(256) void k_anxw(const float* __restrict__ A,
                                              const float* __restrict__ dinv,
                                              const float* __restrict__ xw,
                                              const float* __restrict__ bias,
                                              float* __restrict__ out,
                                              int n, int F, int dorelu) {
  int b = blockIdx.y, i0 = blockIdx.x * 4, t = threadIdx.x;
  __shared__ float sA[4 * 256];
  const float* Ab = A + (size_t)b * n * n;
  const float* dv = dinv + (size_t)b * n;
  for (int idx = t; idx < 4 * n; idx += 256) {
    int il = idx / n, j = idx - il * n;
    sA[il * n + j] = Ab[(size_t)(i0 + il) * n + j] * dv[j];
  }
  __syncthreads();
  const float* xwb = xw + (size_t)b * n * F;
  for (int idx = t; idx < 4 * F; idx += 256) {
    int il = idx / F, f = idx - il * F;
    int i = i0 + il;
    const float* sr = &sA[il * n];
    float acc = 0.f;
    for (int j = 0; j < n; j++) acc += sr[j] * xwb[(size_t)j * F + f];
    float di = dv[i];
    float v = di * acc + 2.f * di * di * xwb[(size_t)i * F + f] + bias[f];
    if (dorelu) v = fmaxf(v, 0.f);
    out[((size_t)b * n + i) * F + f] = v;
  }
}

// ---------- fused pooling: score + exact top-k rank + gather ----------
__global__ __launch_bounds__(256) void k_pool(const float* __restrict__ H,
                                              const float* __restrict__ p,
                                              int* __restrict__ perm,
                                              float* __restrict__ Hout,
                                              int n, int k) {
  int b = blockIdx.x, t = threadIdx.x;
  __shared__ float s[256];
  __shared__ int sord[128];
  float pn = 0.f;
  #pragma unroll
  for (int j = 0; j < HID; j++) pn += p[j] * p[j];
  if (t < n) {
    const float* hr = H + ((size_t)b * n + t) * HID;
    float acc = 0.f;
    #pragma unroll
    for (int j = 0; j < HID; j++) acc += hr[j] * p[j];
    s[t] = tanhf(acc / sqrtf(pn));
  }
  __syncthreads();
  if (t < n) {
    float v = s[t];
    int r = 0;
    for (int j = 0; j < n; j++) {
      float u = s[j];
      r += (u > v) || (u == v && j < t);
    }
    if (r < k) { perm[(size_t)b * k + r] = t; sord[r] = t; }
  }
  __syncthreads();
  for (int idx = t; idx < k * HID; idx += 256) {
    int r = idx / HID, f = idx - r * HID;
    int pi = sord[r];
    Hout[((size_t)b * k + r) * HID + f] = H[((size_t)b * n + pi) * HID + f] * s[pi];
  }
}

// ---------- decoder scatter-add ----------
__global__ __launch_bounds__(256) void k_scatter(const int* __restrict__ perm,
                                                 const float* __restrict__ Hsrc,
                                                 float* __restrict__ Hdst,
                                                 int n, int k, int total) {
  int idx = blockIdx.x * 256 + threadIdx.x;
  if (idx >= total) return;
  int f = idx % HID;
  int r = (idx / HID) % k;
  int b = idx / (HID * k);
  int pi = perm[(size_t)b * k + r];
  Hdst[((size_t)b * n + pi) * HID + f] += Hsrc[idx];
}

// ---------- fused head (reads precomputed sp[b][30][97]) ----------
__global__ __launch_bounds__(256) void k_head2(const float* __restrict__ spg,
                                               const float* __restrict__ c1W,
                                               const float* __restrict__ c1b,
                                               const float* __restrict__ c2W,
                                               const float* __restrict__ c2b,
                                               const float* __restrict__ oW,
                                               const float* __restrict__ ob,
                                               float* __restrict__ out) {
  int b = blockIdx.x, t = threadIdx.x;
  __shared__ float sp[30 * 97];
  __shared__ float y1[16 * 30];
  __shared__ float yp[16 * 15];
  __shared__ float yc[32 * 11];
  const float* spb = spg + (size_t)b * 30 * 97;
  for (int idx = t; idx < 30 * 97; idx += 256) sp[idx] = spb[idx];
  __syncthreads();
  for (int idx = t; idx < 16 * 30; idx += 256) {
    int c = idx / 30, kk = idx - c * 30;
    float a = c1b[c];
    for (int d = 0; d < 97; d++) a += sp[kk * 97 + d] * c1W[c * 97 + d];
    y1[c * 30 + kk] = fmaxf(a, 0.f);
  }
  __syncthreads();
  for (int idx = t; idx < 16 * 15; idx += 256) {
    int c = idx / 15, t2 = idx - c * 15;
    yp[idx] = fmaxf(y1[c * 30 + 2 * t2], y1[c * 30 + 2 * t2 + 1]);
  }
  __syncthreads();
  for (int idx = t; idx < 32 * 11; idx += 256) {
    int o = idx / 11, t3 = idx - o * 11;
    float a = c2b[o];
    for (int i2 = 0; i2 < 16; i2++)
      for (int w = 0; w < 5; w++)
        a += yp[i2 * 15 + t3 + w] * c2W[(o * 16 + i2) * 5 + w];
    yc[o * 11 + t3] = fmaxf(a, 0.f);
  }
  __syncthreads();
  if (t < 32) {
    float a = ob[t];
    for (int q = 0; q < 352; q++) a += yc[q] * oW[q * 32 + t];
    out[(size_t)b * 32 + t] = fmaxf(a, 0.f);
  }
}

extern "C" void kernel_launch(void* const* d_in, const int* in_sizes, int n_in,
                              void* d_out, int out_size, void* d_ws, size_t ws_size,
                              hipStream_t stream) {
  const float* x   = (const float*)d_in[0];
  const float* A0  = (const float*)d_in[1];
  const float* dW0 = (const float*)d_in[2];
  const float* db0 = (const float*)d_in[3];
  const float* dW  = (const float*)d_in[4];
  const float* dbv = (const float*)d_in[5];
  const float* pp  = (const float*)d_in[6];
  const float* uW  = (const float*)d_in[7];
  const float* ub  = (const float*)d_in[8];
  const float* uWl = (const float*)d_in[9];
  const float* ubl = (const float*)d_in[10];
  const float* c1W = (const float*)d_in[11];
  const float* c1b = (const float*)d_in[12];
  const float* c2W = (const float*)d_in[13];
  const float* c2b = (const float*)d_in[14];
  const float* oW  = (const float*)d_in[15];
  const float* ob  = (const float*)d_in[16];
  float* out = (float*)d_out;

  float* base = (float*)d_ws;
  size_t off = 0;
  auto alloc = [&](size_t nel) { nel = (nel + 3) & ~(size_t)3; float* p = base + off; off += nel; return p; };
  float* H0 = alloc((size_t)BATCH * 256 * HID);
  float* H1 = alloc((size_t)BATCH * 128 * HID);
  float* H2 = alloc((size_t)BATCH * 64 * HID);
  float* H3 = alloc((size_t)BATCH * 32 * HID);
  float* H4 = alloc((size_t)BATCH * 16 * HID);
  float* XW = alloc((size_t)BATCH * 256 * DOUT);
  float* A2 = alloc((size_t)BATCH * 64 * 64);
  float* A3 = alloc((size_t)BATCH * 32 * 32);
  float* A4 = alloc((size_t)BATCH * 16 * 16);
  float* D0 = alloc((size_t)BATCH * 256);
  float* D1 = alloc((size_t)BATCH * 128);
  float* D2 = alloc((size_t)BATCH * 64);
  float* D3 = alloc((size_t)BATCH * 32);
  float* D4 = alloc((size_t)BATCH * 16);
  float* COL = alloc((size_t)BATCH * 256);
  float* SP  = alloc((size_t)BATCH * 30 * 97);
  int* P1 = (int*)alloc((size_t)BATCH * 128);
  int* P2 = (int*)alloc((size_t)BATCH * 64);
  int* P3 = (int*)alloc((size_t)BATCH * 32);
  int* P4 = (int*)alloc((size_t)BATCH * 16);
  int* ORD = (int*)alloc((size_t)BATCH * 30 + 2);
  unsigned short* Abf0 = (unsigned short*)alloc((size_t)BATCH * 256 * 256 / 2);
  unsigned short* Abf1 = (unsigned short*)alloc((size_t)BATCH * 128 * 128 / 2);
  unsigned short* Yth  = (unsigned short*)alloc((size_t)BATCH * 112 * 256 / 2);
  unsigned short* Ytl  = (unsigned short*)alloc((size_t)BATCH * 112 * 256 / 2);
  unsigned short* Wp   = (unsigned short*)alloc((size_t)3 * WTOT / 2 + 4);

  int ns[5] = {256, 128, 64, 32, 16};
  float* Hl[5] = {H0, H1, H2, H3, H4};
  float* Al[5] = {nullptr, nullptr, A2, A3, A4};
  float* Dl[5] = {D0, D1, D2, D3, D4};
  int* Pl[4] = {P1, P2, P3, P4};

  // ---- prologue ----
  k_prepA<<<BATCH * 256 / 4, 256, 0, stream>>>(A0, Abf0, D0, BATCH * 256);
  k_splitW3<<<(WTOT + 255) / 256, 256, 0, stream>>>(dW0, dW, uW, uWl, Wp);

  // ---- first GCN: xws (Yt only), gcn2 ITP=2 ----
  {
    k_xws<4><<<BATCH * 256 / 64, 256, 0, stream>>>(x, Wp + WOFF_DW0, nullptr,
                                                   D0, Yth, Ytl, FIN, HID, 48, 8);
    k_gcn2<8, 2><<<BATCH * 2, 256, 0, stream>>>(Abf0, D0, Yth, Ytl, db0, H0, HID, 48, 1);
  }

  // ---- encoder levels ----
  for (int i = 0; i < 4; i++) {
    int n = ns[i], kk = ns[i + 1];
    k_pool<<<BATCH, 256, 0, stream>>>(Hl[i], pp + i * HID, Pl[i], Hl[i + 1], n, kk);
    if (i == 0) {
      int nT = BATCH * 8 * 8;
      k_aug_mfma<<<(nT + 3) / 4, 256, 0, stream>>>(Abf0, P1, nullptr, Abf1, 256, 128, nT);
      k_dinv_bf<<<BATCH * 128 / 4, 256, 0, stream>>>(Abf1, D1, 128, BATCH * 128);
    } else if (i == 1) {
      int nT = BATCH * 4 * 4;
      k_aug_mfma<<<(nT + 3) / 4, 256, 0, stream>>>(Abf1, P2, A2, nullptr, 128, 64, nT);
      k_dinv<<<BATCH * 64 / 4, 256, 0, stream>>>(A2, D2, 64, BATCH * 64);
    } else {
      k_aug<<<dim3(kk / 4, BATCH), 256, 0, stream>>>(Al[i], Pl[i], Al[i + 1], n, kk);
      k_dinv<<<(BATCH * kk + 3) / 4, 256, 0, stream>>>(Al[i + 1], Dl[i + 1], kk, BATCH * kk);
    }
    if (kk == 128) {
      k_xws<2><<<BATCH * kk / 64, 256, 0, stream>>>(Hl[i + 1], Wp + WOFF_DW + i * 3072,
                                                    nullptr, D1, Yth, Ytl, HID, HID, 48, 7);
      k_gcn2<4, 1><<<BATCH * 2, 256, 0, stream>>>(Abf1, D1, Yth, Ytl, dbv + i * HID,
                                                  Hl[i + 1], HID, 48, 1);
    } else {
      k_xws<2><<<BATCH * kk / 64, 256, 0, stream>>>(Hl[i + 1], Wp + WOFF_DW + i * 3072,
                                                    XW, nullptr, nullptr, nullptr,
                                                    HID, HID, 48, 0);
      k_anxw<<<dim3(kk / 4, BATCH), 256, 0, stream>>>(Al[i + 1], Dl[i + 1], XW,
                                                      dbv + i * HID, Hl[i + 1], kk, HID, 1);
    }
  }

  // ---- decoder ----
  for (int i = 0; i < 4; i++) {
    int j = 3 - i, nj = ns[j], kj = ns[j + 1];
    k_scatter<<<(BATCH * kj * HID + 255) / 256, 256, 0, stream>>>(Pl[j], Hl[j + 1], Hl[j],
                                                                  nj, kj, BATCH * kj * HID);
    if (i < 3) {
      if (nj == 128) {
        k_xws<2><<<BATCH * nj / 64, 256, 0, stream>>>(Hl[j], Wp + WOFF_UW + i * 3072,
                                                      nullptr, D1, Yth, Ytl, HID, HID, 48, 7);
        k_gcn2<4, 1><<<BATCH * 2, 256, 0, stream>>>(Abf1, D1, Yth, Ytl, ub + i * HID,
                                                    Hl[j], HID, 48, 1);
      } else {
        k_xws<2><<<BATCH * nj / 64, 256, 0, stream>>>(Hl[j], Wp + WOFF_UW + i * 3072,
                                                      XW, nullptr, nullptr, nullptr,
                                                      HID, HID, 48, 0);
        k_anxw<<<dim3(nj / 4, BATCH), 256, 0, stream>>>(Al[j], Dl[j], XW, ub + i * HID,
                                                        Hl[j], nj, HID, 1);
      }
    } else {
      // final GCN: only col-96 (ranking) for all nodes + full rows for top-30
      k_xws<2><<<BATCH * 256 / 64, 256, 0, stream>>>(H0, Wp + WOFF_UWL, nullptr,
                                                     D0, Yth, Ytl, HID, DOUT, 112, 8);
      k_hcol<<<BATCH * 256 / 4, 256, 0, stream>>>(Abf0, D0, Yth, Ytl, COL);
      k_hsel<<<BATCH, 256, 0, stream>>>(COL, ORD);
      k_hrow<<<BATCH, 256, 0, stream>>>(Abf0, D0, ORD, Yth, Ytl, ubl, SP);
    }
  }

  // ---- fused head ----
  k_head2<<<BATCH, 256, 0, stream>>>(SP, c1W, c1b, c2W, c2b, oW, ob, out);
}

// Round 13
// 532.625 us; speedup vs baseline: 1.0753x; 1.0171x over previous
//
#include <hip/hip_runtime.h>
#include <math.h>

#define BATCH 256
#define NNODE 256
#define FIN   128
#define HID   48
#define DOUT  97

// packed transposed weight planes (ushort elements, per-plane offsets)
#define WOFF_DW0 0        // dW0^T [48][128]
#define WOFF_DW  6144     // dW[i]^T 4 x [48][64]
#define WOFF_UW  18432    // uW[i]^T 3 x [48][64]
#define WOFF_UWL 27648    // uWl^T  [112][64]
#define WTOT     34816    // per-plane stride

typedef __attribute__((ext_vector_type(8))) short bf16x8_t;
typedef __attribute__((ext_vector_type(4))) float f32x4_t;

__device__ inline unsigned short f2bf(float x) {
  unsigned u = __float_as_uint(x);
  u += 0x7fff + ((u >> 16) & 1);
  return (unsigned short)(u >> 16);
}
__device__ inline float bf2f(unsigned short h) {
  return __uint_as_float(((unsigned)h) << 16);
}

// ---------- fused A0 pass: bf16 convert + rowsum -> dinv (exact: 0/1 entries) ----------
__global__ __launch_bounds__(256) void k_prepA(const float* __restrict__ A,
                                               unsigned short* __restrict__ Abf,
                                               float* __restrict__ dinv, int rows) {
  int wid = (blockIdx.x * 256 + threadIdx.x) >> 6;
  int lane = threadIdx.x & 63;
  if (wid >= rows) return;
  const float4* rp = (const float4*)(A + (size_t)wid * 256);
  float4 v = rp[lane];
  unsigned long long pk = (unsigned long long)f2bf(v.x)
                        | ((unsigned long long)f2bf(v.y) << 16)
                        | ((unsigned long long)f2bf(v.z) << 32)
                        | ((unsigned long long)f2bf(v.w) << 48);
  *(unsigned long long*)(Abf + (size_t)wid * 256 + lane * 4) = pk;
  float s = v.x + v.y + v.z + v.w;
  #pragma unroll
  for (int o = 32; o > 0; o >>= 1) s += __shfl_down(s, o);
  if (lane == 0) dinv[wid] = 1.0f / sqrtf(s + 2.0f);
}

// ---------- dinv from bf16 integer adjacency (exact) ----------
__global__ __launch_bounds__(256) void k_dinv_bf(const unsigned short* __restrict__ Abf,
                                                 float* __restrict__ dinv, int n, int rows) {
  int wid = (blockIdx.x * 256 + threadIdx.x) >> 6;
  int lane = threadIdx.x & 63;
  if (wid >= rows) return;
  const unsigned short* row = Abf + (size_t)wid * n;
  float s = 0.f;
  for (int j = lane * 2; j < n; j += 128) {
    unsigned u = *(const unsigned*)(row + j);
    s += bf2f((unsigned short)(u & 0xffffu)) + bf2f((unsigned short)(u >> 16));
  }
  #pragma unroll
  for (int o = 32; o > 0; o >>= 1) s += __shfl_down(s, o);
  if (lane == 0) dinv[wid] = 1.0f / sqrtf(s + 2.0f);
}

// ---------- rowsum -> dinv (fp32 A, deeper levels) ----------
__global__ __launch_bounds__(256) void k_dinv(const float* __restrict__ A,
                                              float* __restrict__ dinv,
                                              int n, int rows) {
  int wid  = (blockIdx.x * blockDim.x + threadIdx.x) >> 6;
  int lane = threadIdx.x & 63;
  if (wid >= rows) return;
  const float* row = A + (size_t)wid * n;
  float s = 0.f;
  for (int j = lane; j < n; j += 64) s += row[j];
  #pragma unroll
  for (int o = 32; o > 0; o >>= 1) s += __shfl_down(s, o);
  if (lane == 0) dinv[wid] = 1.0f / sqrtf(s + 2.0f);
}

// ---------- transpose + 3-plane split ALL weights (runs once, tiny) ----------
__global__ __launch_bounds__(256) void k_splitW3(const float* __restrict__ dW0,
                                                 const float* __restrict__ dW,
                                                 const float* __restrict__ uW,
                                                 const float* __restrict__ uWl,
                                                 unsigned short* __restrict__ Wp) {
  int idx = blockIdx.x * 256 + threadIdx.x;
  if (idx >= WTOT) return;
  float v;
  if (idx < WOFF_DW) {                   // dW0^T [48][128]
    int f = idx / 128, kk = idx - f * 128;
    v = dW0[kk * HID + f];
  } else if (idx < WOFF_UW) {            // dW[i]^T [48][64]
    int r = idx - WOFF_DW;
    int i = r / 3072; r -= i * 3072;
    int f = r / 64, kk = r - f * 64;
    v = (kk < HID) ? dW[((size_t)i * HID + kk) * HID + f] : 0.f;
  } else if (idx < WOFF_UWL) {           // uW[i]^T [48][64]
    int r = idx - WOFF_UW;
    int i = r / 3072; r -= i * 3072;
    int f = r / 64, kk = r - f * 64;
    v = (kk < HID) ? uW[((size_t)i * HID + kk) * HID + f] : 0.f;
  } else {                               // uWl^T [112][64]
    int r = idx - WOFF_UWL;
    int f = r / 64, kk = r - f * 64;
    v = (f < DOUT && kk < HID) ? uWl[(size_t)kk * DOUT + f] : 0.f;
  }
  unsigned short h = f2bf(v);
  float r1 = v - bf2f(h);
  unsigned short m = f2bf(r1);
  float r2 = r1 - bf2f(m);
  unsigned short l = f2bf(r2);
  Wp[idx] = h;
  Wp[idx + WTOT] = m;
  Wp[idx + 2 * WTOT] = l;
}

// ---------- wave-independent MFMA GEMM XW = X @ W, 3-plane split, NO LDS/barrier ----------
template<int KS2>   // K-steps of 32; KP = KS2*32
__global__ __launch_bounds__(256) void k_xws(const float* __restrict__ X,
                                             const unsigned short* __restrict__ Wp,
                                             float* __restrict__ XW,
                                             const float* __restrict__ dinv,
                                             unsigned short* __restrict__ Yth,
                                             unsigned short* __restrict__ Ytl,
                                             int K, int F, int Fpad, int nShift) {
  constexpr int KP = KS2 * 32;
  int mt = (blockIdx.x * 256 + threadIdx.x) >> 6;
  int lane = threadIdx.x & 63;
  int r = lane & 15, q = lane >> 4;
  const float* xr = X + ((long)mt * 16 + r) * K;
  bf16x8_t ah[KS2], am[KS2], al[KS2];
  #pragma unroll
  for (int ks = 0; ks < KS2; ks++) {
    int col0 = ks * 32 + q * 8;
    float v[8];
    if (col0 + 8 <= K) {
      float4 a = *(const float4*)(xr + col0);
      float4 b = *(const float4*)(xr + col0 + 4);
      v[0] = a.x; v[1] = a.y; v[2] = a.z; v[3] = a.w;
      v[4] = b.x; v[5] = b.y; v[6] = b.z; v[7] = b.w;
    } else {
      #pragma unroll
      for (int j = 0; j < 8; j++) v[j] = (col0 + j < K) ? xr[col0 + j] : 0.f;
    }
    #pragma unroll
    for (int j = 0; j < 8; j++) {
      unsigned short h = f2bf(v[j]);
      float r1 = v[j] - bf2f(h);
      unsigned short m = f2bf(r1);
      float r2 = r1 - bf2f(m);
      unsigned short l = f2bf(r2);
      ah[ks][j] = (short)h;
      am[ks][j] = (short)m;
      al[ks][j] = (short)l;
    }
  }
  long row0 = (long)mt * 16 + q * 4;
  float4 dv4 = {0.f, 0.f, 0.f, 0.f};
  long ytBase = 0;
  if (Yth) {
    dv4 = *(const float4*)(dinv + row0);
    int bb = (int)(row0 >> nShift);
    int jj = (int)(row0 & ((1 << nShift) - 1));
    ytBase = (long)bb * Fpad;
    ytBase = ytBase << nShift;
    ytBase += jj;
  }
  int nFT = Fpad >> 4;
  for (int ft = 0; ft < nFT; ft++) {
    int fl = ft * 16 + r;
    const unsigned short* wb = Wp + (size_t)fl * KP + q * 8;
    f32x4_t acc = {0.f, 0.f, 0.f, 0.f};
    #pragma unroll
    for (int ks = 0; ks < KS2; ks++) {
      bf16x8_t bh = *(const bf16x8_t*)(wb + ks * 32);
      bf16x8_t bm = *(const bf16x8_t*)(wb + WTOT + ks * 32);
      bf16x8_t bl = *(const bf16x8_t*)(wb + 2 * WTOT + ks * 32);
      acc = __builtin_amdgcn_mfma_f32_16x16x32_bf16(ah[ks], bh, acc, 0, 0, 0);
      acc = __builtin_amdgcn_mfma_f32_16x16x32_bf16(ah[ks], bm, acc, 0, 0, 0);
      acc = __builtin_amdgcn_mfma_f32_16x16x32_bf16(am[ks], bh, acc, 0, 0, 0);
      acc = __builtin_amdgcn_mfma_f32_16x16x32_bf16(am[ks], bm, acc, 0, 0, 0);
      acc = __builtin_amdgcn_mfma_f32_16x16x32_bf16(ah[ks], bl, acc, 0, 0, 0);
      acc = __builtin_amdgcn_mfma_f32_16x16x32_bf16(al[ks], bh, acc, 0, 0, 0);
    }
    int f = fl;
    if (f < F) {
      if (XW) {
        #pragma unroll
        for (int reg = 0; reg < 4; reg++) XW[(row0 + reg) * F + f] = acc[reg];
      }
      if (Yth) {
        float dvv[4] = {dv4.x, dv4.y, dv4.z, dv4.w};
        unsigned long long hpk = 0, lpk = 0;
        #pragma unroll
        for (int reg = 0; reg < 4; reg++) {
          float v = dvv[reg] * acc[reg];
          unsigned short hi = f2bf(v);
          unsigned short lo = f2bf(v - bf2f(hi));
          hpk |= ((unsigned long long)hi) << (16 * reg);
          lpk |= ((unsigned long long)lo) << (16 * reg);
        }
        long o = ytBase + ((long)f << nShift);
        *(unsigned long long*)(Yth + o) = hpk;
        *(unsigned long long*)(Ytl + o) = lpk;
      }
    }
  }
}

// ---------- LDS-free fused GCN: ITP it-tiles per wave, A in regs ----------
template<int KS, int ITP>
__global__ __launch_bounds__(256) void k_gcn2(
    const unsigned short* __restrict__ Abf, const float* __restrict__ dinv,
    const unsigned short* __restrict__ Yth, const unsigned short* __restrict__ Ytl,
    const float* __restrict__ bias, float* __restrict__ out,
    int F, int Fpad, int dorelu) {
  constexpr int n = KS * 32;
  int b = blockIdx.x & (BATCH - 1);
  int sub = blockIdx.x >> 8;
  int wave = threadIdx.x >> 6, lane = threadIdx.x & 63;
  int r = lane & 15, q = lane >> 4;
  const float* dv = dinv + (size_t)b * n;
  int itBase = (sub * 4 + wave) * ITP;
  bf16x8_t af[ITP][KS];
  #pragma unroll
  for (int l = 0; l < ITP; l++) {
    const unsigned short* ap = Abf + ((size_t)b * n + (itBase + l) * 16 + r) * n + q * 8;
    #pragma unroll
    for (int ks = 0; ks < KS; ks++) af[l][ks] = *(const bf16x8_t*)(ap + ks * 32);
  }
  float di[ITP][4];
  #pragma unroll
  for (int l = 0; l < ITP; l++) {
    int i0 = (itBase + l) * 16 + q * 4;
    #pragma unroll
    for (int reg = 0; reg < 4; reg++) di[l][reg] = dv[i0 + reg];
  }
  int nFT = Fpad >> 4;
  for (int ft = 0; ft < nFT; ft++) {
    int fl = ft * 16 + r;
    const unsigned short* yrowh = Yth + ((size_t)b * Fpad + fl) * n;
    const unsigned short* yrowl = Ytl + ((size_t)b * Fpad + fl) * n;
    f32x4_t acc[ITP];
    #pragma unroll
    for (int l = 0; l < ITP; l++) acc[l] = (f32x4_t){0.f, 0.f, 0.f, 0.f};
    #pragma unroll
    for (int ks = 0; ks < KS; ks++) {
      bf16x8_t bh = *(const bf16x8_t*)(yrowh + q * 8 + ks * 32);
      bf16x8_t bl = *(const bf16x8_t*)(yrowl + q * 8 + ks * 32);
      #pragma unroll
      for (int l = 0; l < ITP; l++) {
        acc[l] = __builtin_amdgcn_mfma_f32_16x16x32_bf16(af[l][ks], bh, acc[l], 0, 0, 0);
        acc[l] = __builtin_amdgcn_mfma_f32_16x16x32_bf16(af[l][ks], bl, acc[l], 0, 0, 0);
      }
    }
    if (fl < F) {
      float bf = bias[fl];
      #pragma unroll
      for (int l = 0; l < ITP; l++) {
        int i0 = (itBase + l) * 16 + q * 4;
        unsigned long long hq = *(const unsigned long long*)(yrowh + i0);
        unsigned long long lq = *(const unsigned long long*)(yrowl + i0);
        #pragma unroll
        for (int reg = 0; reg < 4; reg++) {
          float yv = bf2f((unsigned short)(hq >> (16 * reg)))
                   + bf2f((unsigned short)(lq >> (16 * reg)));
          float v = di[l][reg] * acc[l][reg] + 2.f * di[l][reg] * yv + bf;
          if (dorelu) v = fmaxf(v, 0.f);
          out[((size_t)b * n + i0 + reg) * F + fl] = v;
        }
      }
    }
  }
}

// ---------- final-GCN column 96 (ranking scores): matvec per node ----------
__global__ __launch_bounds__(256) void k_hcol(const unsigned short* __restrict__ Abf,
                                              const float* __restrict__ dinv,
                                              const unsigned short* __restrict__ Yth,
                                              const unsigned short* __restrict__ Ytl,
                                              float* __restrict__ col) {
  int gw = blockIdx.x * 4 + (threadIdx.x >> 6);   // gw = b*256 + i
  int lane = threadIdx.x & 63;
  int b = gw >> 8, i = gw & 255;
  const unsigned short* ar = Abf + (size_t)gw * 256;
  const unsigned short* yh = Yth + ((size_t)b * 112 + 96) * 256;
  const unsigned short* yl = Ytl + ((size_t)b * 112 + 96) * 256;
  unsigned long long a4 = *(const unsigned long long*)(ar + lane * 4);
  unsigned long long h4 = *(const unsigned long long*)(yh + lane * 4);
  unsigned long long l4 = *(const unsigned long long*)(yl + lane * 4);
  float s = 0.f;
  #pragma unroll
  for (int e = 0; e < 4; e++) {
    float av = bf2f((unsigned short)(a4 >> (16 * e)));
    float yv = bf2f((unsigned short)(h4 >> (16 * e)))
             + bf2f((unsigned short)(l4 >> (16 * e)));
    s += av * yv;
  }
  #pragma unroll
  for (int o = 32; o > 0; o >>= 1) s += __shfl_down(s, o);
  if (lane == 0) {
    float d = dinv[gw];
    float yv = bf2f(yh[i]) + bf2f(yl[i]);
    col[gw] = d * s + 2.f * d * yv;
  }
}

// ---------- exact top-30 rank over col-96 scores ----------
__global__ __launch_bounds__(256) void k_hsel(const float* __restrict__ col,
                                              int* __restrict__ ord) {
  int b = blockIdx.x, t = threadIdx.x;
  __shared__ float s[256];
  s[t] = col[(size_t)b * 256 + t];
  __syncthreads();
  float v = s[t];
  int r = 0;
  for (int j = 0; j < 256; j++) {
    float u = s[j];
    r += (u > v) || (u == v && j < t);
  }
  if (r < 30) ord[(size_t)b * 30 + r] = t;
}

// ---------- final-GCN rows for top-30 nodes only (gathered-A MFMA) ----------
__global__ __launch_bounds__(256) void k_hrow(const unsigned short* __restrict__ Abf,
                                              const float* __restrict__ dinv,
                                              const int* __restrict__ ord,
                                              const unsigned short* __restrict__ Yth,
                                              const unsigned short* __restrict__ Ytl,
                                              const float* __restrict__ ubl,
                                              float* __restrict__ sp) {
  int b = blockIdx.x;
  int wave = threadIdx.x >> 6, lane = threadIdx.x & 63;
  int it = wave & 1, fh = wave >> 1;
  int r = lane & 15, q = lane >> 4;
  const int* po = ord + (size_t)b * 30;
  int ari = it * 16 + r;
  int arow = po[ari < 30 ? ari : 0];
  const unsigned short* ap = Abf + ((size_t)b * 256 + arow) * 256 + q * 8;
  bf16x8_t af[8];
  #pragma unroll
  for (int ks = 0; ks < 8; ks++) af[ks] = *(const bf16x8_t*)(ap + ks * 32);
  int ftBeg = fh * 4, ftEnd = fh ? 7 : 4;
  for (int ft = ftBeg; ft < ftEnd; ft++) {
    int fl = ft * 16 + r;
    const unsigned short* yrowh = Yth + ((size_t)b * 112 + fl) * 256;
    const unsigned short* yrowl = Ytl + ((size_t)b * 112 + fl) * 256;
    f32x4_t acc = {0.f, 0.f, 0.f, 0.f};
    #pragma unroll
    for (int ks = 0; ks < 8; ks++) {
      bf16x8_t bh = *(const bf16x8_t*)(yrowh + q * 8 + ks * 32);
      bf16x8_t bl = *(const bf16x8_t*)(yrowl + q * 8 + ks * 32);
      acc = __builtin_amdgcn_mfma_f32_16x16x32_bf16(af[ks], bh, acc, 0, 0, 0);
      acc = __builtin_amdgcn_mfma_f32_16x16x32_bf16(af[ks], bl, acc, 0, 0, 0);
    }
    if (fl < DOUT) {
      float bf = ubl[fl];
      #pragma unroll
      for (int reg = 0; reg < 4; reg++) {
        int rowidx = it * 16 + q * 4 + reg;
        if (rowidx < 30) {
          int node = po[rowidx];
          float d = dinv[(size_t)b * 256 + node];
          float yv = bf2f(yrowh[node]) + bf2f(yrowl[node]);
          sp[((size_t)b * 30 + rowidx) * DOUT + fl] = d * acc[reg] + 2.f * d * yv + bf;
        }
      }
    }
  }
}

// ---------- MFMA augment (EXACT integer arithmetic), XCD-swizzled ----------
// grid must be (kt*kt/4) * 256 blocks; all blocks of one batch share blockIdx%8 (one XCD)
// so the batch's gathered A-rows are fetched into exactly one L2.
__global__ __launch_bounds__(256) void k_aug_mfma(const unsigned short* __restrict__ Abf,
                                                  const int* __restrict__ perm,
                                                  float* __restrict__ Ap,
                                                  unsigned short* __restrict__ Apbf,
                                                  int n, int k) {
  int kt = k >> 4;
  int inner = blockIdx.x & 255;
  int slot = blockIdx.x >> 8;
  int b = ((inner & 7) << 5) | (inner >> 3);
  int wave = threadIdx.x >> 6, lane = threadIdx.x & 63;
  int tile = slot * 4 + wave;
  int it = tile / kt, ft = tile - it * kt;
  int r = lane & 15, q = lane >> 4;
  const int* pm = perm + (size_t)b * k;
  int rowA = pm[it * 16 + r];
  int rowB = pm[ft * 16 + r];
  const unsigned short* Ab = Abf + (size_t)b * n * n;
  const unsigned short* pa = Ab + (size_t)rowA * n + q * 8;
  const unsigned short* pb = Ab + (size_t)rowB * n + q * 8;
  f32x4_t acc = {0.f, 0.f, 0.f, 0.f};
  for (int k0 = 0; k0 < n; k0 += 32) {
    bf16x8_t a  = *(const bf16x8_t*)(pa + k0);
    bf16x8_t bv = *(const bf16x8_t*)(pb + k0);
    acc = __builtin_amdgcn_mfma_f32_16x16x32_bf16(a, bv, acc, 0, 0, 0);
  }
  int c = ft * 16 + r;
  const unsigned short* rowBp = Ab + (size_t)rowB * n;
  #pragma unroll
  for (int reg = 0; reg < 4; reg++) {
    int rr = it * 16 + q * 4 + reg;
    int pr = pm[rr];
    float v = acc[reg] + 2.f * bf2f(rowBp[pr]);
    if (rr == c) v = 0.f;
    if (Ap)   Ap[((size_t)b * k + rr) * k + c] = v;
    if (Apbf) Apbf[((size_t)b * k + rr) * k + c] = f2bf(v);
  }
}

// ---------- VALU augment for tiny levels ----------
__global__ __launch_bounds__(256) void k_aug(const float* __restrict__ A,
                                             const int* __restrict__ perm,
                                             float* __restrict__ Ap,
                                             int n, int k) {
  int b = blockIdx.y, r0 = blockIdx.x * 4, t = threadIdx.x;
  __shared__ float sR[4 * 256];
  __shared__ int spm[4];
  const float* Ab = A + (size_t)b * n * n;
  if (t < 4) spm[t] = perm[(size_t)b * k + r0 + t];
  __syncthreads();
  for (int idx = t; idx < 4 * n; idx += 256) {
    int rl = idx / n, j = idx - rl * n;
    sR[rl * n + j] = Ab[(size_t)spm[rl] * n + j];
  }
  __syncthreads();
  for (int c = t; c < k; c += 256) {
    int pc = perm[(size_t)b * k + c];
    const float* rowc = Ab + (size_t)pc * n;
    float a0 = 0.f, a1 = 0.f, a2 = 0.f, a3 = 0.f;
    for (int j = 0; j < n; j++) {
      float v = rowc[j];
      a0 += sR[j] * v;
      a1 += sR[n + j] * v;
      a2 += sR[2 * n + j] * v;
      a3 += sR[3 * n + j] * v;
    }
    float accs[4] = {a0, a1, a2, a3};
    for (int rl = 0; rl < 4; rl++) {
      int r = r0 + rl;
      float res = accs[rl] + 2.f * Ab[(size_t)spm[rl] * n + pc];
      Ap[((size_t)b * k + r) * k + c] = (r == c) ? 0.f : res;
    }
  }
}

// ---------- VALU anxw for small n ----------
__global__ __launch_bounds__(256) void k_anxw(const float* __restrict__ A,
                                              const float* __restrict__ dinv,
                                              const float* __restrict__ xw,
                                              const float* __restrict__ bias,
                                              float* __restrict__ out,
                                              int n, int F, int dorelu) {
  int b = blockIdx.y, i0 = blockIdx.x * 4, t = threadIdx.x;
  __shared__ float sA[4 * 256];
  const float* Ab = A + (size_t)b * n * n;
  const float* dv = dinv + (size_t)b * n;
  for (int idx = t; idx < 4 * n; idx += 256) {
    int il = idx / n, j = idx - il * n;
    sA[il * n + j] = Ab[(size_t)(i0 + il) * n + j] * dv[j];
  }
  __syncthreads();
  const float* xwb = xw + (size_t)b * n * F;
  for (int idx = t; idx < 4 * F; idx += 256) {
    int il = idx / F, f = idx - il * F;
    int i = i0 + il;
    const float* sr = &sA[il * n];
    float acc = 0.f;
    for (int j = 0; j < n; j++) acc += sr[j] * xwb[(size_t)j * F + f];
    float di = dv[i];
    float v = di * acc + 2.f * di * di * xwb[(size_t)i * F + f] + bias[f];
    if (dorelu) v = fmaxf(v, 0.f);
    out[((size_t)b * n + i) * F + f] = v;
  }
}

// ---------- fused pooling: score + exact top-k rank + gather ----------
__global__ __launch_bounds__(256) void k_pool(const float* __restrict__ H,
                                              const float* __restrict__ p,
                                              int* __restrict__ perm,
                                              float* __restrict__ Hout,
                                              int n, int k) {
  int b = blockIdx.x, t = threadIdx.x;
  __shared__ float s[256];
  __shared__ int sord[128];
  float pn = 0.f;
  #pragma unroll
  for (int j = 0; j < HID; j++) pn += p[j] * p[j];
  if (t < n) {
    const float* hr = H + ((size_t)b * n + t) * HID;
    float acc = 0.f;
    #pragma unroll
    for (int j = 0; j < HID; j++) acc += hr[j] * p[j];
    s[t] = tanhf(acc / sqrtf(pn));
  }
  __syncthreads();
  if (t < n) {
    float v = s[t];
    int r = 0;
    for (int j = 0; j < n; j++) {
      float u = s[j];
      r += (u > v) || (u == v && j < t);
    }
    if (r < k) { perm[(size_t)b * k + r] = t; sord[r] = t; }
  }
  __syncthreads();
  for (int idx = t; idx < k * HID; idx += 256) {
    int r = idx / HID, f = idx - r * HID;
    int pi = sord[r];
    Hout[((size_t)b * k + r) * HID + f] = H[((size_t)b * n + pi) * HID + f] * s[pi];
  }
}

// ---------- decoder scatter-add ----------
__global__ __launch_bounds__(256) void k_scatter(const int* __restrict__ perm,
                                                 const float* __restrict__ Hsrc,
                                                 float* __restrict__ Hdst,
                                                 int n, int k, int total) {
  int idx = blockIdx.x * 256 + threadIdx.x;
  if (idx >= total) return;
  int f = idx % HID;
  int r = (idx / HID) % k;
  int b = idx / (HID * k);
  int pi = perm[(size_t)b * k + r];
  Hdst[((size_t)b * n + pi) * HID + f] += Hsrc[idx];
}

// ---------- fused head (reads precomputed sp[b][30][97]) ----------
__global__ __launch_bounds__(256) void k_head2(const float* __restrict__ spg,
                                               const float* __restrict__ c1W,
                                               const float* __restrict__ c1b,
                                               const float* __restrict__ c2W,
                                               const float* __restrict__ c2b,
                                               const float* __restrict__ oW,
                                               const float* __restrict__ ob,
                                               float* __restrict__ out) {
  int b = blockIdx.x, t = threadIdx.x;
  __shared__ float sp[30 * 97];
  __shared__ float y1[16 * 30];
  __shared__ float yp[16 * 15];
  __shared__ float yc[32 * 11];
  const float* spb = spg + (size_t)b * 30 * 97;
  for (int idx = t; idx < 30 * 97; idx += 256) sp[idx] = spb[idx];
  __syncthreads();
  for (int idx = t; idx < 16 * 30; idx += 256) {
    int c = idx / 30, kk = idx - c * 30;
    float a = c1b[c];
    for (int d = 0; d < 97; d++) a += sp[kk * 97 + d] * c1W[c * 97 + d];
    y1[c * 30 + kk] = fmaxf(a, 0.f);
  }
  __syncthreads();
  for (int idx = t; idx < 16 * 15; idx += 256) {
    int c = idx / 15, t2 = idx - c * 15;
    yp[idx] = fmaxf(y1[c * 30 + 2 * t2], y1[c * 30 + 2 * t2 + 1]);
  }
  __syncthreads();
  for (int idx = t; idx < 32 * 11; idx += 256) {
    int o = idx / 11, t3 = idx - o * 11;
    float a = c2b[o];
    for (int i2 = 0; i2 < 16; i2++)
      for (int w = 0; w < 5; w++)
        a += yp[i2 * 15 + t3 + w] * c2W[(o * 16 + i2) * 5 + w];
    yc[o * 11 + t3] = fmaxf(a, 0.f);
  }
  __syncthreads();
  if (t < 32) {
    float a = ob[t];
    for (int q = 0; q < 352; q++) a += yc[q] * oW[q * 32 + t];
    out[(size_t)b * 32 + t] = fmaxf(a, 0.f);
  }
}

extern "C" void kernel_launch(void* const* d_in, const int* in_sizes, int n_in,
                              void* d_out, int out_size, void* d_ws, size_t ws_size,
                              hipStream_t stream) {
  const float* x   = (const float*)d_in[0];
  const float* A0  = (const float*)d_in[1];
  const float* dW0 = (const float*)d_in[2];
  const float* db0 = (const float*)d_in[3];
  const float* dW  = (const float*)d_in[4];
  const float* dbv = (const float*)d_in[5];
  const float* pp  = (const float*)d_in[6];
  const float* uW  = (const float*)d_in[7];
  const float* ub  = (const float*)d_in[8];
  const float* uWl = (const float*)d_in[9];
  const float* ubl = (const float*)d_in[10];
  const float* c1W = (const float*)d_in[11];
  const float* c1b = (const float*)d_in[12];
  const float* c2W = (const float*)d_in[13];
  const float* c2b = (const float*)d_in[14];
  const float* oW  = (const float*)d_in[15];
  const float* ob  = (const float*)d_in[16];
  float* out = (float*)d_out;

  float* base = (float*)d_ws;
  size_t off = 0;
  auto alloc = [&](size_t nel) { nel = (nel + 3) & ~(size_t)3; float* p = base + off; off += nel; return p; };
  float* H0 = alloc((size_t)BATCH * 256 * HID);
  float* H1 = alloc((size_t)BATCH * 128 * HID);
  float* H2 = alloc((size_t)BATCH * 64 * HID);
  float* H3 = alloc((size_t)BATCH * 32 * HID);
  float* H4 = alloc((size_t)BATCH * 16 * HID);
  float* XW = alloc((size_t)BATCH * 256 * DOUT);
  float* A2 = alloc((size_t)BATCH * 64 * 64);
  float* A3 = alloc((size_t)BATCH * 32 * 32);
  float* A4 = alloc((size_t)BATCH * 16 * 16);
  float* D0 = alloc((size_t)BATCH * 256);
  float* D1 = alloc((size_t)BATCH * 128);
  float* D2 = alloc((size_t)BATCH * 64);
  float* D3 = alloc((size_t)BATCH * 32);
  float* D4 = alloc((size_t)BATCH * 16);
  float* COL = alloc((size_t)BATCH * 256);
  float* SP  = alloc((size_t)BATCH * 30 * 97);
  int* P1 = (int*)alloc((size_t)BATCH * 128);
  int* P2 = (int*)alloc((size_t)BATCH * 64);
  int* P3 = (int*)alloc((size_t)BATCH * 32);
  int* P4 = (int*)alloc((size_t)BATCH * 16);
  int* ORD = (int*)alloc((size_t)BATCH * 30 + 2);
  unsigned short* Abf0 = (unsigned short*)alloc((size_t)BATCH * 256 * 256 / 2);
  unsigned short* Abf1 = (unsigned short*)alloc((size_t)BATCH * 128 * 128 / 2);
  unsigned short* Yth  = (unsigned short*)alloc((size_t)BATCH * 112 * 256 / 2);
  unsigned short* Ytl  = (unsigned short*)alloc((size_t)BATCH * 112 * 256 / 2);
  unsigned short* Wp   = (unsigned short*)alloc((size_t)3 * WTOT / 2 + 4);

  int ns[5] = {256, 128, 64, 32, 16};
  float* Hl[5] = {H0, H1, H2, H3, H4};
  float* Al[5] = {nullptr, nullptr, A2, A3, A4};
  float* Dl[5] = {D0, D1, D2, D3, D4};
  int* Pl[4] = {P1, P2, P3, P4};

  // ---- prologue ----
  k_prepA<<<BATCH * 256 / 4, 256, 0, stream>>>(A0, Abf0, D0, BATCH * 256);
  k_splitW3<<<(WTOT + 255) / 256, 256, 0, stream>>>(dW0, dW, uW, uWl, Wp);

  // ---- first GCN: xws (Yt only), gcn2 ITP=2 ----
  {
    k_xws<4><<<BATCH * 256 / 64, 256, 0, stream>>>(x, Wp + WOFF_DW0, nullptr,
                                                   D0, Yth, Ytl, FIN, HID, 48, 8);
    k_gcn2<8, 2><<<BATCH * 2, 256, 0, stream>>>(Abf0, D0, Yth, Ytl, db0, H0, HID, 48, 1);
  }

  // ---- encoder levels ----
  for (int i = 0; i < 4; i++) {
    int n = ns[i], kk = ns[i + 1];
    k_pool<<<BATCH, 256, 0, stream>>>(Hl[i], pp + i * HID, Pl[i], Hl[i + 1], n, kk);
    if (i == 0) {
      // grid = (kt*kt/4)*256 = 16*256 ; XCD-swizzled
      k_aug_mfma<<<16 * 256, 256, 0, stream>>>(Abf0, P1, nullptr, Abf1, 256, 128);
      k_dinv_bf<<<BATCH * 128 / 4, 256, 0, stream>>>(Abf1, D1, 128, BATCH * 128);
    } else if (i == 1) {
      // grid = (4*4/4)*256 = 4*256
      k_aug_mfma<<<4 * 256, 256, 0, stream>>>(Abf1, P2, A2, nullptr, 128, 64);
      k_dinv<<<BATCH * 64 / 4, 256, 0, stream>>>(A2, D2, 64, BATCH * 64);
    } else {
      k_aug<<<dim3(kk / 4, BATCH), 256, 0, stream>>>(Al[i], Pl[i], Al[i + 1], n, kk);
      k_dinv<<<(BATCH * kk + 3) / 4, 256, 0, stream>>>(Al[i + 1], Dl[i + 1], kk, BATCH * kk);
    }
    if (kk == 128) {
      k_xws<2><<<BATCH * kk / 64, 256, 0, stream>>>(Hl[i + 1], Wp + WOFF_DW + i * 3072,
                                                    nullptr, D1, Yth, Ytl, HID, HID, 48, 7);
      k_gcn2<4, 1><<<BATCH * 2, 256, 0, stream>>>(Abf1, D1, Yth, Ytl, dbv + i * HID,
                                                  Hl[i + 1], HID, 48, 1);
    } else {
      k_xws<2><<<BATCH * kk / 64, 256, 0, stream>>>(Hl[i + 1], Wp + WOFF_DW + i * 3072,
                                                    XW, nullptr, nullptr, nullptr,
                                                    HID, HID, 48, 0);
      k_anxw<<<dim3(kk / 4, BATCH), 256, 0, stream>>>(Al[i + 1], Dl[i + 1], XW,
                                                      dbv + i * HID, Hl[i + 1], kk, HID, 1);
    }
  }

  // ---- decoder ----
  for (int i = 0; i < 4; i++) {
    int j = 3 - i, nj = ns[j], kj = ns[j + 1];
    k_scatter<<<(BATCH * kj * HID + 255) / 256, 256, 0, stream>>>(Pl[j], Hl[j + 1], Hl[j],
                                                                  nj, kj, BATCH * kj * HID);
    if (i < 3) {
      if (nj == 128) {
        k_xws<2><<<BATCH * nj / 64, 256, 0, stream>>>(Hl[j], Wp + WOFF_UW + i * 3072,
                                                      nullptr, D1, Yth, Ytl, HID, HID, 48, 7);
        k_gcn2<4, 1><<<BATCH * 2, 256, 0, stream>>>(Abf1, D1, Yth, Ytl, ub + i * HID,
                                                    Hl[j], HID, 48, 1);
      } else {
        k_xws<2><<<BATCH * nj / 64, 256, 0, stream>>>(Hl[j], Wp + WOFF_UW + i * 3072,
                                                      XW, nullptr, nullptr, nullptr,
                                                      HID, HID, 48, 0);
        k_anxw<<<dim3(nj / 4, BATCH), 256, 0, stream>>>(Al[j], Dl[j], XW, ub + i * HID,
                                                        Hl[j], nj, HID, 1);
      }
    } else {
      // final GCN: only col-96 (ranking) for all nodes + full rows for top-30
      k_xws<2><<<BATCH * 256 / 64, 256, 0, stream>>>(H0, Wp + WOFF_UWL, nullptr,
                                                     D0, Yth, Ytl, HID, DOUT, 112, 8);
      k_hcol<<<BATCH * 256 / 4, 256, 0, stream>>>(Abf0, D0, Yth, Ytl, COL);
      k_hsel<<<BATCH, 256, 0, stream>>>(COL, ORD);
      k_hrow<<<BATCH, 256, 0, stream>>>(Abf0, D0, ORD, Yth, Ytl, ubl, SP);
    }
  }

  // ---- fused head ----
  k_head2<<<BATCH, 256, 0, stream>>>(SP, c1W, c1b, c2W, c2b, oW, ob, out);
}

// Round 14
// 523.211 us; speedup vs baseline: 1.0946x; 1.0180x over previous
//
#include <hip/hip_runtime.h>
#include <math.h>

#define BATCH 256
#define NNODE 256
#define FIN   128
#define HID   48
#define DOUT  97

// packed transposed weight planes (ushort elements, per-plane offsets)
#define WOFF_DW0 0        // dW0^T [48][128]
#define WOFF_DW  6144     // dW[i]^T 4 x [48][64]
#define WOFF_UW  18432    // uW[i]^T 3 x [48][64]
#define WOFF_UWL 27648    // uWl^T  [112][64]
#define WTOT     34816    // per-plane stride

typedef __attribute__((ext_vector_type(8))) short bf16x8_t;
typedef __attribute__((ext_vector_type(4))) float f32x4_t;

__device__ inline unsigned short f2bf(float x) {
  unsigned u = __float_as_uint(x);
  u += 0x7fff + ((u >> 16) & 1);
  return (unsigned short)(u >> 16);
}
__device__ inline float bf2f(unsigned short h) {
  return __uint_as_float(((unsigned)h) << 16);
}

// ---------- fused A0 pass: bf16 convert + rowsum -> dinv (exact: 0/1 entries) ----------
__global__ __launch_bounds__(256) void k_prepA(const float* __restrict__ A,
                                               unsigned short* __restrict__ Abf,
                                               float* __restrict__ dinv, int rows) {
  int wid = (blockIdx.x * 256 + threadIdx.x) >> 6;
  int lane = threadIdx.x & 63;
  if (wid >= rows) return;
  const float4* rp = (const float4*)(A + (size_t)wid * 256);
  float4 v = rp[lane];
  unsigned long long pk = (unsigned long long)f2bf(v.x)
                        | ((unsigned long long)f2bf(v.y) << 16)
                        | ((unsigned long long)f2bf(v.z) << 32)
                        | ((unsigned long long)f2bf(v.w) << 48);
  *(unsigned long long*)(Abf + (size_t)wid * 256 + lane * 4) = pk;
  float s = v.x + v.y + v.z + v.w;
  #pragma unroll
  for (int o = 32; o > 0; o >>= 1) s += __shfl_down(s, o);
  if (lane == 0) dinv[wid] = 1.0f / sqrtf(s + 2.0f);
}

// ---------- dinv from bf16 integer adjacency (exact) ----------
__global__ __launch_bounds__(256) void k_dinv_bf(const unsigned short* __restrict__ Abf,
                                                 float* __restrict__ dinv, int n, int rows) {
  int wid = (blockIdx.x * 256 + threadIdx.x) >> 6;
  int lane = threadIdx.x & 63;
  if (wid >= rows) return;
  const unsigned short* row = Abf + (size_t)wid * n;
  float s = 0.f;
  for (int j = lane * 2; j < n; j += 128) {
    unsigned u = *(const unsigned*)(row + j);
    s += bf2f((unsigned short)(u & 0xffffu)) + bf2f((unsigned short)(u >> 16));
  }
  #pragma unroll
  for (int o = 32; o > 0; o >>= 1) s += __shfl_down(s, o);
  if (lane == 0) dinv[wid] = 1.0f / sqrtf(s + 2.0f);
}

// ---------- rowsum -> dinv (fp32 A, deeper levels) ----------
__global__ __launch_bounds__(256) void k_dinv(const float* __restrict__ A,
                                              float* __restrict__ dinv,
                                              int n, int rows) {
  int wid  = (blockIdx.x * blockDim.x + threadIdx.x) >> 6;
  int lane = threadIdx.x & 63;
  if (wid >= rows) return;
  const float* row = A + (size_t)wid * n;
  float s = 0.f;
  for (int j = lane; j < n; j += 64) s += row[j];
  #pragma unroll
  for (int o = 32; o > 0; o >>= 1) s += __shfl_down(s, o);
  if (lane == 0) dinv[wid] = 1.0f / sqrtf(s + 2.0f);
}

// ---------- transpose + 3-plane split ALL weights (runs once, tiny) ----------
__global__ __launch_bounds__(256) void k_splitW3(const float* __restrict__ dW0,
                                                 const float* __restrict__ dW,
                                                 const float* __restrict__ uW,
                                                 const float* __restrict__ uWl,
                                                 unsigned short* __restrict__ Wp) {
  int idx = blockIdx.x * 256 + threadIdx.x;
  if (idx >= WTOT) return;
  float v;
  if (idx < WOFF_DW) {                   // dW0^T [48][128]
    int f = idx / 128, kk = idx - f * 128;
    v = dW0[kk * HID + f];
  } else if (idx < WOFF_UW) {            // dW[i]^T [48][64]
    int r = idx - WOFF_DW;
    int i = r / 3072; r -= i * 3072;
    int f = r / 64, kk = r - f * 64;
    v = (kk < HID) ? dW[((size_t)i * HID + kk) * HID + f] : 0.f;
  } else if (idx < WOFF_UWL) {           // uW[i]^T [48][64]
    int r = idx - WOFF_UW;
    int i = r / 3072; r -= i * 3072;
    int f = r / 64, kk = r - f * 64;
    v = (kk < HID) ? uW[((size_t)i * HID + kk) * HID + f] : 0.f;
  } else {                               // uWl^T [112][64]
    int r = idx - WOFF_UWL;
    int f = r / 64, kk = r - f * 64;
    v = (f < DOUT && kk < HID) ? uWl[(size_t)kk * DOUT + f] : 0.f;
  }
  unsigned short h = f2bf(v);
  float r1 = v - bf2f(h);
  unsigned short m = f2bf(r1);
  float r2 = r1 - bf2f(m);
  unsigned short l = f2bf(r2);
  Wp[idx] = h;
  Wp[idx + WTOT] = m;
  Wp[idx + 2 * WTOT] = l;
}

// ---------- wave-independent MFMA GEMM XW = X @ W, 3-plane split, NO LDS/barrier ----------
template<int KS2>   // K-steps of 32; KP = KS2*32
__global__ __launch_bounds__(256) void k_xws(const float* __restrict__ X,
                                             const unsigned short* __restrict__ Wp,
                                             float* __restrict__ XW,
                                             const float* __restrict__ dinv,
                                             unsigned short* __restrict__ Yth,
                                             unsigned short* __restrict__ Ytl,
                                             int K, int F, int Fpad, int nShift) {
  constexpr int KP = KS2 * 32;
  int mt = (blockIdx.x * 256 + threadIdx.x) >> 6;
  int lane = threadIdx.x & 63;
  int r = lane & 15, q = lane >> 4;
  const float* xr = X + ((long)mt * 16 + r) * K;
  bf16x8_t ah[KS2], am[KS2], al[KS2];
  #pragma unroll
  for (int ks = 0; ks < KS2; ks++) {
    int col0 = ks * 32 + q * 8;
    float v[8];
    if (col0 + 8 <= K) {
      float4 a = *(const float4*)(xr + col0);
      float4 b = *(const float4*)(xr + col0 + 4);
      v[0] = a.x; v[1] = a.y; v[2] = a.z; v[3] = a.w;
      v[4] = b.x; v[5] = b.y; v[6] = b.z; v[7] = b.w;
    } else {
      #pragma unroll
      for (int j = 0; j < 8; j++) v[j] = (col0 + j < K) ? xr[col0 + j] : 0.f;
    }
    #pragma unroll
    for (int j = 0; j < 8; j++) {
      unsigned short h = f2bf(v[j]);
      float r1 = v[j] - bf2f(h);
      unsigned short m = f2bf(r1);
      float r2 = r1 - bf2f(m);
      unsigned short l = f2bf(r2);
      ah[ks][j] = (short)h;
      am[ks][j] = (short)m;
      al[ks][j] = (short)l;
    }
  }
  long row0 = (long)mt * 16 + q * 4;
  float4 dv4 = {0.f, 0.f, 0.f, 0.f};
  long ytBase = 0;
  if (Yth) {
    dv4 = *(const float4*)(dinv + row0);
    int bb = (int)(row0 >> nShift);
    int jj = (int)(row0 & ((1 << nShift) - 1));
    ytBase = (long)bb * Fpad;
    ytBase = ytBase << nShift;
    ytBase += jj;
  }
  int nFT = Fpad >> 4;
  for (int ft = 0; ft < nFT; ft++) {
    int fl = ft * 16 + r;
    const unsigned short* wb = Wp + (size_t)fl * KP + q * 8;
    f32x4_t acc = {0.f, 0.f, 0.f, 0.f};
    #pragma unroll
    for (int ks = 0; ks < KS2; ks++) {
      bf16x8_t bh = *(const bf16x8_t*)(wb + ks * 32);
      bf16x8_t bm = *(const bf16x8_t*)(wb + WTOT + ks * 32);
      bf16x8_t bl = *(const bf16x8_t*)(wb + 2 * WTOT + ks * 32);
      acc = __builtin_amdgcn_mfma_f32_16x16x32_bf16(ah[ks], bh, acc, 0, 0, 0);
      acc = __builtin_amdgcn_mfma_f32_16x16x32_bf16(ah[ks], bm, acc, 0, 0, 0);
      acc = __builtin_amdgcn_mfma_f32_16x16x32_bf16(am[ks], bh, acc, 0, 0, 0);
      acc = __builtin_amdgcn_mfma_f32_16x16x32_bf16(am[ks], bm, acc, 0, 0, 0);
      acc = __builtin_amdgcn_mfma_f32_16x16x32_bf16(ah[ks], bl, acc, 0, 0, 0);
      acc = __builtin_amdgcn_mfma_f32_16x16x32_bf16(al[ks], bh, acc, 0, 0, 0);
    }
    int f = fl;
    if (f < F) {
      if (XW) {
        #pragma unroll
        for (int reg = 0; reg < 4; reg++) XW[(row0 + reg) * F + f] = acc[reg];
      }
      if (Yth) {
        float dvv[4] = {dv4.x, dv4.y, dv4.z, dv4.w};
        unsigned long long hpk = 0, lpk = 0;
        #pragma unroll
        for (int reg = 0; reg < 4; reg++) {
          float v = dvv[reg] * acc[reg];
          unsigned short hi = f2bf(v);
          unsigned short lo = f2bf(v - bf2f(hi));
          hpk |= ((unsigned long long)hi) << (16 * reg);
          lpk |= ((unsigned long long)lo) << (16 * reg);
        }
        long o = ytBase + ((long)f << nShift);
        *(unsigned long long*)(Yth + o) = hpk;
        *(unsigned long long*)(Ytl + o) = lpk;
      }
    }
  }
}

// ---------- LDS-free fused GCN: ITP it-tiles per wave, A in regs ----------
template<int KS, int ITP>
__global__ __launch_bounds__(256) void k_gcn2(
    const unsigned short* __restrict__ Abf, const float* __restrict__ dinv,
    const unsigned short* __restrict__ Yth, const unsigned short* __restrict__ Ytl,
    const float* __restrict__ bias, float* __restrict__ out,
    int F, int Fpad, int dorelu) {
  constexpr int n = KS * 32;
  int b = blockIdx.x & (BATCH - 1);
  int sub = blockIdx.x >> 8;
  int wave = threadIdx.x >> 6, lane = threadIdx.x & 63;
  int r = lane & 15, q = lane >> 4;
  const float* dv = dinv + (size_t)b * n;
  int itBase = (sub * 4 + wave) * ITP;
  bf16x8_t af[ITP][KS];
  #pragma unroll
  for (int l = 0; l < ITP; l++) {
    const unsigned short* ap = Abf + ((size_t)b * n + (itBase + l) * 16 + r) * n + q * 8;
    #pragma unroll
    for (int ks = 0; ks < KS; ks++) af[l][ks] = *(const bf16x8_t*)(ap + ks * 32);
  }
  float di[ITP][4];
  #pragma unroll
  for (int l = 0; l < ITP; l++) {
    int i0 = (itBase + l) * 16 + q * 4;
    #pragma unroll
    for (int reg = 0; reg < 4; reg++) di[l][reg] = dv[i0 + reg];
  }
  int nFT = Fpad >> 4;
  for (int ft = 0; ft < nFT; ft++) {
    int fl = ft * 16 + r;
    const unsigned short* yrowh = Yth + ((size_t)b * Fpad + fl) * n;
    const unsigned short* yrowl = Ytl + ((size_t)b * Fpad + fl) * n;
    f32x4_t acc[ITP];
    #pragma unroll
    for (int l = 0; l < ITP; l++) acc[l] = (f32x4_t){0.f, 0.f, 0.f, 0.f};
    #pragma unroll
    for (int ks = 0; ks < KS; ks++) {
      bf16x8_t bh = *(const bf16x8_t*)(yrowh + q * 8 + ks * 32);
      bf16x8_t bl = *(const bf16x8_t*)(yrowl + q * 8 + ks * 32);
      #pragma unroll
      for (int l = 0; l < ITP; l++) {
        acc[l] = __builtin_amdgcn_mfma_f32_16x16x32_bf16(af[l][ks], bh, acc[l], 0, 0, 0);
        acc[l] = __builtin_amdgcn_mfma_f32_16x16x32_bf16(af[l][ks], bl, acc[l], 0, 0, 0);
      }
    }
    if (fl < F) {
      float bf = bias[fl];
      #pragma unroll
      for (int l = 0; l < ITP; l++) {
        int i0 = (itBase + l) * 16 + q * 4;
        unsigned long long hq = *(const unsigned long long*)(yrowh + i0);
        unsigned long long lq = *(const unsigned long long*)(yrowl + i0);
        #pragma unroll
        for (int reg = 0; reg < 4; reg++) {
          float yv = bf2f((unsigned short)(hq >> (16 * reg)))
                   + bf2f((unsigned short)(lq >> (16 * reg)));
          float v = di[l][reg] * acc[l][reg] + 2.f * di[l][reg] * yv + bf;
          if (dorelu) v = fmaxf(v, 0.f);
          out[((size_t)b * n + i0 + reg) * F + fl] = v;
        }
      }
    }
  }
}

// ---------- final-GCN column 96 (ranking scores): matvec per node ----------
__global__ __launch_bounds__(256) void k_hcol(const unsigned short* __restrict__ Abf,
                                              const float* __restrict__ dinv,
                                              const unsigned short* __restrict__ Yth,
                                              const unsigned short* __restrict__ Ytl,
                                              float* __restrict__ col) {
  int gw = blockIdx.x * 4 + (threadIdx.x >> 6);   // gw = b*256 + i
  int lane = threadIdx.x & 63;
  int b = gw >> 8, i = gw & 255;
  const unsigned short* ar = Abf + (size_t)gw * 256;
  const unsigned short* yh = Yth + ((size_t)b * 112 + 96) * 256;
  const unsigned short* yl = Ytl + ((size_t)b * 112 + 96) * 256;
  unsigned long long a4 = *(const unsigned long long*)(ar + lane * 4);
  unsigned long long h4 = *(const unsigned long long*)(yh + lane * 4);
  unsigned long long l4 = *(const unsigned long long*)(yl + lane * 4);
  float s = 0.f;
  #pragma unroll
  for (int e = 0; e < 4; e++) {
    float av = bf2f((unsigned short)(a4 >> (16 * e)));
    float yv = bf2f((unsigned short)(h4 >> (16 * e)))
             + bf2f((unsigned short)(l4 >> (16 * e)));
    s += av * yv;
  }
  #pragma unroll
  for (int o = 32; o > 0; o >>= 1) s += __shfl_down(s, o);
  if (lane == 0) {
    float d = dinv[gw];
    float yv = bf2f(yh[i]) + bf2f(yl[i]);
    col[gw] = d * s + 2.f * d * yv;
  }
}

// ---------- exact top-30 rank over col-96 scores ----------
__global__ __launch_bounds__(256) void k_hsel(const float* __restrict__ col,
                                              int* __restrict__ ord) {
  int b = blockIdx.x, t = threadIdx.x;
  __shared__ float s[256];
  s[t] = col[(size_t)b * 256 + t];
  __syncthreads();
  float v = s[t];
  int r = 0;
  for (int j = 0; j < 256; j++) {
    float u = s[j];
    r += (u > v) || (u == v && j < t);
  }
  if (r < 30) ord[(size_t)b * 30 + r] = t;
}

// ---------- final-GCN rows for top-30 nodes only (gathered-A MFMA) ----------
__global__ __launch_bounds__(256) void k_hrow(const unsigned short* __restrict__ Abf,
                                              const float* __restrict__ dinv,
                                              const int* __restrict__ ord,
                                              const unsigned short* __restrict__ Yth,
                                              const unsigned short* __restrict__ Ytl,
                                              const float* __restrict__ ubl,
                                              float* __restrict__ sp) {
  int b = blockIdx.x;
  int wave = threadIdx.x >> 6, lane = threadIdx.x & 63;
  int it = wave & 1, fh = wave >> 1;
  int r = lane & 15, q = lane >> 4;
  const int* po = ord + (size_t)b * 30;
  int ari = it * 16 + r;
  int arow = po[ari < 30 ? ari : 0];
  const unsigned short* ap = Abf + ((size_t)b * 256 + arow) * 256 + q * 8;
  bf16x8_t af[8];
  #pragma unroll
  for (int ks = 0; ks < 8; ks++) af[ks] = *(const bf16x8_t*)(ap + ks * 32);
  int ftBeg = fh * 4, ftEnd = fh ? 7 : 4;
  for (int ft = ftBeg; ft < ftEnd; ft++) {
    int fl = ft * 16 + r;
    const unsigned short* yrowh = Yth + ((size_t)b * 112 + fl) * 256;
    const unsigned short* yrowl = Ytl + ((size_t)b * 112 + fl) * 256;
    f32x4_t acc = {0.f, 0.f, 0.f, 0.f};
    #pragma unroll
    for (int ks = 0; ks < 8; ks++) {
      bf16x8_t bh = *(const bf16x8_t*)(yrowh + q * 8 + ks * 32);
      bf16x8_t bl = *(const bf16x8_t*)(yrowl + q * 8 + ks * 32);
      acc = __builtin_amdgcn_mfma_f32_16x16x32_bf16(af[ks], bh, acc, 0, 0, 0);
      acc = __builtin_amdgcn_mfma_f32_16x16x32_bf16(af[ks], bl, acc, 0, 0, 0);
    }
    if (fl < DOUT) {
      float bf = ubl[fl];
      #pragma unroll
      for (int reg = 0; reg < 4; reg++) {
        int rowidx = it * 16 + q * 4 + reg;
        if (rowidx < 30) {
          int node = po[rowidx];
          float d = dinv[(size_t)b * 256 + node];
          float yv = bf2f(yrowh[node]) + bf2f(yrowl[node]);
          sp[((size_t)b * 30 + rowidx) * DOUT + fl] = d * acc[reg] + 2.f * d * yv + bf;
        }
      }
    }
  }
}

// ---------- MFMA augment via M=A+I trick (EXACT), XCD-swizzled ----------
// A diag is 0 at every level, so M[pr][pr]=1: patch the fragment element at column==row
// to bf16(1.0). Then M_r . M_c = A^2[pr,pc] + 2A[pr,pc] (+delta on diag, zeroed anyway)
// -> NO epilogue gather of A[pr][pc]. grid = (kt*kt/4)*256; batch = swizzled (one XCD).
__global__ __launch_bounds__(256) void k_aug_mfma(const unsigned short* __restrict__ Abf,
                                                  const int* __restrict__ perm,
                                                  float* __restrict__ Ap,
                                                  unsigned short* __restrict__ Apbf,
                                                  int n, int k) {
  int kt = k >> 4;
  int inner = blockIdx.x & 255;
  int slot = blockIdx.x >> 8;
  int b = ((inner & 7) << 5) | (inner >> 3);
  int wave = threadIdx.x >> 6, lane = threadIdx.x & 63;
  int tile = slot * 4 + wave;
  int it = tile / kt, ft = tile - it * kt;
  int r = lane & 15, q = lane >> 4;
  const int* pm = perm + (size_t)b * k;
  int rowA = pm[it * 16 + r];
  int rowB = pm[ft * 16 + r];
  const unsigned short* Ab = Abf + (size_t)b * n * n;
  const unsigned short* pa = Ab + (size_t)rowA * n + q * 8;
  const unsigned short* pb = Ab + (size_t)rowB * n + q * 8;
  f32x4_t acc = {0.f, 0.f, 0.f, 0.f};
  for (int k0 = 0; k0 < n; k0 += 32) {
    bf16x8_t a  = *(const bf16x8_t*)(pa + k0);
    bf16x8_t bv = *(const bf16x8_t*)(pb + k0);
    int daA = rowA - k0 - q * 8;
    int daB = rowB - k0 - q * 8;
    #pragma unroll
    for (int e = 0; e < 8; e++) {
      if (daA == e) a[e] = (short)0x3F80;   // bf16(1.0)
      if (daB == e) bv[e] = (short)0x3F80;
    }
    acc = __builtin_amdgcn_mfma_f32_16x16x32_bf16(a, bv, acc, 0, 0, 0);
  }
  int c = ft * 16 + r;
  #pragma unroll
  for (int reg = 0; reg < 4; reg++) {
    int rr = it * 16 + q * 4 + reg;
    float v = acc[reg];
    if (rr == c) v = 0.f;
    if (Ap)   Ap[((size_t)b * k + rr) * k + c] = v;
    if (Apbf) Apbf[((size_t)b * k + rr) * k + c] = f2bf(v);
  }
}

// ---------- VALU augment for tiny levels ----------
__global__ __launch_bounds__(256) void k_aug(const float* __restrict__ A,
                                             const int* __restrict__ perm,
                                             float* __restrict__ Ap,
                                             int n, int k) {
  int b = blockIdx.y, r0 = blockIdx.x * 4, t = threadIdx.x;
  __shared__ float sR[4 * 256];
  __shared__ int spm[4];
  const float* Ab = A + (size_t)b * n * n;
  if (t < 4) spm[t] = perm[(size_t)b * k + r0 + t];
  __syncthreads();
  for (int idx = t; idx < 4 * n; idx += 256) {
    int rl = idx / n, j = idx - rl * n;
    sR[rl * n + j] = Ab[(size_t)spm[rl] * n + j];
  }
  __syncthreads();
  for (int c = t; c < k; c += 256) {
    int pc = perm[(size_t)b * k + c];
    const float* rowc = Ab + (size_t)pc * n;
    float a0 = 0.f, a1 = 0.f, a2 = 0.f, a3 = 0.f;
    for (int j = 0; j < n; j++) {
      float v = rowc[j];
      a0 += sR[j] * v;
      a1 += sR[n + j] * v;
      a2 += sR[2 * n + j] * v;
      a3 += sR[3 * n + j] * v;
    }
    float accs[4] = {a0, a1, a2, a3};
    for (int rl = 0; rl < 4; rl++) {
      int r = r0 + rl;
      float res = accs[rl] + 2.f * Ab[(size_t)spm[rl] * n + pc];
      Ap[((size_t)b * k + r) * k + c] = (r == c) ? 0.f : res;
    }
  }
}

// ---------- VALU anxw for small n ----------
__global__ __launch_bounds__(256) void k_anxw(const float* __restrict__ A,
                                              const float* __restrict__ dinv,
                                              const float* __restrict__ xw,
                                              const float* __restrict__ bias,
                                              float* __restrict__ out,
                                              int n, int F, int dorelu) {
  int b = blockIdx.y, i0 = blockIdx.x * 4, t = threadIdx.x;
  __shared__ float sA[4 * 256];
  const float* Ab = A + (size_t)b * n * n;
  const float* dv = dinv + (size_t)b * n;
  for (int idx = t; idx < 4 * n; idx += 256) {
    int il = idx / n, j = idx - il * n;
    sA[il * n + j] = Ab[(size_t)(i0 + il) * n + j] * dv[j];
  }
  __syncthreads();
  const float* xwb = xw + (size_t)b * n * F;
  for (int idx = t; idx < 4 * F; idx += 256) {
    int il = idx / F, f = idx - il * F;
    int i = i0 + il;
    const float* sr = &sA[il * n];
    float acc = 0.f;
    for (int j = 0; j < n; j++) acc += sr[j] * xwb[(size_t)j * F + f];
    float di = dv[i];
    float v = di * acc + 2.f * di * di * xwb[(size_t)i * F + f] + bias[f];
    if (dorelu) v = fmaxf(v, 0.f);
    out[((size_t)b * n + i) * F + f] = v;
  }
}

// ---------- fused pooling: score + exact top-k rank + gather ----------
__global__ __launch_bounds__(256) void k_pool(const float* __restrict__ H,
                                              const float* __restrict__ p,
                                              int* __restrict__ perm,
                                              float* __restrict__ Hout,
                                              int n, int k) {
  int b = blockIdx.x, t = threadIdx.x;
  __shared__ float s[256];
  __shared__ int sord[128];
  float pn = 0.f;
  #pragma unroll
  for (int j = 0; j < HID; j++) pn += p[j] * p[j];
  if (t < n) {
    const float* hr = H + ((size_t)b * n + t) * HID;
    float acc = 0.f;
    #pragma unroll
    for (int j = 0; j < HID; j++) acc += hr[j] * p[j];
    s[t] = tanhf(acc / sqrtf(pn));
  }
  __syncthreads();
  if (t < n) {
    float v = s[t];
    int r = 0;
    for (int j = 0; j < n; j++) {
      float u = s[j];
      r += (u > v) || (u == v && j < t);
    }
    if (r < k) { perm[(size_t)b * k + r] = t; sord[r] = t; }
  }
  __syncthreads();
  for (int idx = t; idx < k * HID; idx += 256) {
    int r = idx / HID, f = idx - r * HID;
    int pi = sord[r];
    Hout[((size_t)b * k + r) * HID + f] = H[((size_t)b * n + pi) * HID + f] * s[pi];
  }
}

// ---------- decoder scatter-add ----------
__global__ __launch_bounds__(256) void k_scatter(const int* __restrict__ perm,
                                                 const float* __restrict__ Hsrc,
                                                 float* __restrict__ Hdst,
                                                 int n, int k, int total) {
  int idx = blockIdx.x * 256 + threadIdx.x;
  if (idx >= total) return;
  int f = idx % HID;
  int r = (idx / HID) % k;
  int b = idx / (HID * k);
  int pi = perm[(size_t)b * k + r];
  Hdst[((size_t)b * n + pi) * HID + f] += Hsrc[idx];
}

// ---------- fused head (reads precomputed sp[b][30][97]) ----------
__global__ __launch_bounds__(256) void k_head2(const float* __restrict__ spg,
                                               const float* __restrict__ c1W,
                                               const float* __restrict__ c1b,
                                               const float* __restrict__ c2W,
                                               const float* __restrict__ c2b,
                                               const float* __restrict__ oW,
                                               const float* __restrict__ ob,
                                               float* __restrict__ out) {
  int b = blockIdx.x, t = threadIdx.x;
  __shared__ float sp[30 * 97];
  __shared__ float y1[16 * 30];
  __shared__ float yp[16 * 15];
  __shared__ float yc[32 * 11];
  const float* spb = spg + (size_t)b * 30 * 97;
  for (int idx = t; idx < 30 * 97; idx += 256) sp[idx] = spb[idx];
  __syncthreads();
  for (int idx = t; idx < 16 * 30; idx += 256) {
    int c = idx / 30, kk = idx - c * 30;
    float a = c1b[c];
    for (int d = 0; d < 97; d++) a += sp[kk * 97 + d] * c1W[c * 97 + d];
    y1[c * 30 + kk] = fmaxf(a, 0.f);
  }
  __syncthreads();
  for (int idx = t; idx < 16 * 15; idx += 256) {
    int c = idx / 15, t2 = idx - c * 15;
    yp[idx] = fmaxf(y1[c * 30 + 2 * t2], y1[c * 30 + 2 * t2 + 1]);
  }
  __syncthreads();
  for (int idx = t; idx < 32 * 11; idx += 256) {
    int o = idx / 11, t3 = idx - o * 11;
    float a = c2b[o];
    for (int i2 = 0; i2 < 16; i2++)
      for (int w = 0; w < 5; w++)
        a += yp[i2 * 15 + t3 + w] * c2W[(o * 16 + i2) * 5 + w];
    yc[o * 11 + t3] = fmaxf(a, 0.f);
  }
  __syncthreads();
  if (t < 32) {
    float a = ob[t];
    for (int q = 0; q < 352; q++) a += yc[q] * oW[q * 32 + t];
    out[(size_t)b * 32 + t] = fmaxf(a, 0.f);
  }
}

extern "C" void kernel_launch(void* const* d_in, const int* in_sizes, int n_in,
                              void* d_out, int out_size, void* d_ws, size_t ws_size,
                              hipStream_t stream) {
  const float* x   = (const float*)d_in[0];
  const float* A0  = (const float*)d_in[1];
  const float* dW0 = (const float*)d_in[2];
  const float* db0 = (const float*)d_in[3];
  const float* dW  = (const float*)d_in[4];
  const float* dbv = (const float*)d_in[5];
  const float* pp  = (const float*)d_in[6];
  const float* uW  = (const float*)d_in[7];
  const float* ub  = (const float*)d_in[8];
  const float* uWl = (const float*)d_in[9];
  const float* ubl = (const float*)d_in[10];
  const float* c1W = (const float*)d_in[11];
  const float* c1b = (const float*)d_in[12];
  const float* c2W = (const float*)d_in[13];
  const float* c2b = (const float*)d_in[14];
  const float* oW  = (const float*)d_in[15];
  const float* ob  = (const float*)d_in[16];
  float* out = (float*)d_out;

  float* base = (float*)d_ws;
  size_t off = 0;
  auto alloc = [&](size_t nel) { nel = (nel + 3) & ~(size_t)3; float* p = base + off; off += nel; return p; };
  float* H0 = alloc((size_t)BATCH * 256 * HID);
  float* H1 = alloc((size_t)BATCH * 128 * HID);
  float* H2 = alloc((size_t)BATCH * 64 * HID);
  float* H3 = alloc((size_t)BATCH * 32 * HID);
  float* H4 = alloc((size_t)BATCH * 16 * HID);
  float* XW = alloc((size_t)BATCH * 256 * DOUT);
  float* A2 = alloc((size_t)BATCH * 64 * 64);
  float* A3 = alloc((size_t)BATCH * 32 * 32);
  float* A4 = alloc((size_t)BATCH * 16 * 16);
  float* D0 = alloc((size_t)BATCH * 256);
  float* D1 = alloc((size_t)BATCH * 128);
  float* D2 = alloc((size_t)BATCH * 64);
  float* D3 = alloc((size_t)BATCH * 32);
  float* D4 = alloc((size_t)BATCH * 16);
  float* COL = alloc((size_t)BATCH * 256);
  float* SP  = alloc((size_t)BATCH * 30 * 97);
  int* P1 = (int*)alloc((size_t)BATCH * 128);
  int* P2 = (int*)alloc((size_t)BATCH * 64);
  int* P3 = (int*)alloc((size_t)BATCH * 32);
  int* P4 = (int*)alloc((size_t)BATCH * 16);
  int* ORD = (int*)alloc((size_t)BATCH * 30 + 2);
  unsigned short* Abf0 = (unsigned short*)alloc((size_t)BATCH * 256 * 256 / 2);
  unsigned short* Abf1 = (unsigned short*)alloc((size_t)BATCH * 128 * 128 / 2);
  unsigned short* Yth  = (unsigned short*)alloc((size_t)BATCH * 112 * 256 / 2);
  unsigned short* Ytl  = (unsigned short*)alloc((size_t)BATCH * 112 * 256 / 2);
  unsigned short* Wp   = (unsigned short*)alloc((size_t)3 * WTOT / 2 + 4);

  int ns[5] = {256, 128, 64, 32, 16};
  float* Hl[5] = {H0, H1, H2, H3, H4};
  float* Al[5] = {nullptr, nullptr, A2, A3, A4};
  float* Dl[5] = {D0, D1, D2, D3, D4};
  int* Pl[4] = {P1, P2, P3, P4};

  // ---- prologue ----
  k_prepA<<<BATCH * 256 / 4, 256, 0, stream>>>(A0, Abf0, D0, BATCH * 256);
  k_splitW3<<<(WTOT + 255) / 256, 256, 0, stream>>>(dW0, dW, uW, uWl, Wp);

  // ---- first GCN: xws (Yt only), gcn2 ITP=2 ----
  {
    k_xws<4><<<BATCH * 256 / 64, 256, 0, stream>>>(x, Wp + WOFF_DW0, nullptr,
                                                   D0, Yth, Ytl, FIN, HID, 48, 8);
    k_gcn2<8, 2><<<BATCH * 2, 256, 0, stream>>>(Abf0, D0, Yth, Ytl, db0, H0, HID, 48, 1);
  }

  // ---- encoder levels ----
  for (int i = 0; i < 4; i++) {
    int n = ns[i], kk = ns[i + 1];
    k_pool<<<BATCH, 256, 0, stream>>>(Hl[i], pp + i * HID, Pl[i], Hl[i + 1], n, kk);
    if (i == 0) {
      // grid = (kt*kt/4)*256 = 16*256 ; XCD-swizzled
      k_aug_mfma<<<16 * 256, 256, 0, stream>>>(Abf0, P1, nullptr, Abf1, 256, 128);
      k_dinv_bf<<<BATCH * 128 / 4, 256, 0, stream>>>(Abf1, D1, 128, BATCH * 128);
    } else if (i == 1) {
      // grid = (4*4/4)*256 = 4*256
      k_aug_mfma<<<4 * 256, 256, 0, stream>>>(Abf1, P2, A2, nullptr, 128, 64);
      k_dinv<<<BATCH * 64 / 4, 256, 0, stream>>>(A2, D2, 64, BATCH * 64);
    } else {
      k_aug<<<dim3(kk / 4, BATCH), 256, 0, stream>>>(Al[i], Pl[i], Al[i + 1], n, kk);
      k_dinv<<<(BATCH * kk + 3) / 4, 256, 0, stream>>>(Al[i + 1], Dl[i + 1], kk, BATCH * kk);
    }
    if (kk == 128) {
      k_xws<2><<<BATCH * kk / 64, 256, 0, stream>>>(Hl[i + 1], Wp + WOFF_DW + i * 3072,
                                                    nullptr, D1, Yth, Ytl, HID, HID, 48, 7);
      k_gcn2<4, 1><<<BATCH * 2, 256, 0, stream>>>(Abf1, D1, Yth, Ytl, dbv + i * HID,
                                                  Hl[i + 1], HID, 48, 1);
    } else {
      k_xws<2><<<BATCH * kk / 64, 256, 0, stream>>>(Hl[i + 1], Wp + WOFF_DW + i * 3072,
                                                    XW, nullptr, nullptr, nullptr,
                                                    HID, HID, 48, 0);
      k_anxw<<<dim3(kk / 4, BATCH), 256, 0, stream>>>(Al[i + 1], Dl[i + 1], XW,
                                                      dbv + i * HID, Hl[i + 1], kk, HID, 1);
    }
  }

  // ---- decoder ----
  for (int i = 0; i < 4; i++) {
    int j = 3 - i, nj = ns[j], kj = ns[j + 1];
    k_scatter<<<(BATCH * kj * HID + 255) / 256, 256, 0, stream>>>(Pl[j], Hl[j + 1], Hl[j],
                                                                  nj, kj, BATCH * kj * HID);
    if (i < 3) {
      if (nj == 128) {
        k_xws<2><<<BATCH * nj / 64, 256, 0, stream>>>(Hl[j], Wp + WOFF_UW + i * 3072,
                                                      nullptr, D1, Yth, Ytl, HID, HID, 48, 7);
        k_gcn2<4, 1><<<BATCH * 2, 256, 0, stream>>>(Abf1, D1, Yth, Ytl, ub + i * HID,
                                                    Hl[j], HID, 48, 1);
      } else {
        k_xws<2><<<BATCH * nj / 64, 256, 0, stream>>>(Hl[j], Wp + WOFF_UW + i * 3072,
                                                      XW, nullptr, nullptr, nullptr,
                                                      HID, HID, 48, 0);
        k_anxw<<<dim3(nj / 4, BATCH), 256, 0, stream>>>(Al[j], Dl[j], XW, ub + i * HID,
                                                        Hl[j], nj, HID, 1);
      }
    } else {
      // final GCN: only col-96 (ranking) for all nodes + full rows for top-30
      k_xws<2><<<BATCH * 256 / 64, 256, 0, stream>>>(H0, Wp + WOFF_UWL, nullptr,
                                                     D0, Yth, Ytl, HID, DOUT, 112, 8);
      k_hcol<<<BATCH * 256 / 4, 256, 0, stream>>>(Abf0, D0, Yth, Ytl, COL);
      k_hsel<<<BATCH, 256, 0, stream>>>(COL, ORD);
      k_hrow<<<BATCH, 256, 0, stream>>>(Abf0, D0, ORD, Yth, Ytl, ubl, SP);
    }
  }

  // ---- fused head ----
  k_head2<<<BATCH, 256, 0, stream>>>(SP, c1W, c1b, c2W, c2b, oW, ob, out);
}